// Round 7
// baseline (1006.418 us; speedup 1.0000x reference)
//
#include <hip/hip_runtime.h>
#include <hip/hip_fp16.h>

typedef __attribute__((ext_vector_type(8))) short bf16x8;
typedef __attribute__((ext_vector_type(4))) float f32x4;

__device__ __forceinline__ float frelu(float v){ return fmaxf(v, 0.f); }
__device__ __forceinline__ short f2bf(float f){
  unsigned u = __float_as_uint(f);
  unsigned r = (u + 0x7fffu + ((u>>16)&1u)) >> 16;
  return (short)r;
}
__device__ __forceinline__ float bf2f(short h){
  return __uint_as_float(((unsigned)(unsigned short)h) << 16);
}

// ---------- MFMA split-bf16 GEMM: Out = EPI( PRE(A) @ W.T ) ----------
// PRE: 0 id, 1 relu(a + bpre[k])
// EPI: 1 +bpost, 2 relu(+bpost), 3 relu(+bpost)+A[node][col] (K==BN),
//      4 *dscale[node] (fp32 out), 5 *dscale[node] -> fp16 CHUNK-MAJOR out
//      (tpc[col>>4][node][col&15], slab stride n*16 halfs)
template<int K, int BN, int COLS_REAL, int PRE, int EPI, int WRG, int WCG>
__global__ __launch_bounds__(512) void k_mgemm(const float* __restrict__ A,
    const float* __restrict__ W, const float* __restrict__ bpre,
    const float* __restrict__ bpost, const float* __restrict__ dscale,
    float* __restrict__ Out, int n)
{
  constexpr int BM = WRG*64;
  __shared__ __align__(16) short sAh[BM*32];
  __shared__ __align__(16) short sAl[BM*32];
  __shared__ __align__(16) short sWh[BN*32];
  __shared__ __align__(16) short sWl[BN*32];

  const int tid = threadIdx.x;
  const int nb0 = blockIdx.x * BM;
  const int l = tid & 63;
  const int w = tid >> 6;
  const int wr = w % WRG;
  const int wc = w / WRG;
  const int lrow = l & 15;
  const int koct = l >> 4;

  f32x4 acc[4][4];
  #pragma unroll
  for (int i=0;i<4;i++)
    #pragma unroll
    for (int j=0;j<4;j++) acc[i][j] = (f32x4){0.f,0.f,0.f,0.f};

  for (int kc = 0; kc < K/32; ++kc) {
    if (kc) __syncthreads();
    #pragma unroll
    for (int t = 0; t < BM/128; ++t) {
      int idx = tid + t*512;
      int row = idx >> 2, kq = idx & 3;
      int node = nb0 + row;
      float a[8];
      if (node < n) {
        const float* g = A + (size_t)node*K + kc*32 + kq*8;
        float4 v0 = *(const float4*)g;
        float4 v1 = *(const float4*)(g+4);
        a[0]=v0.x; a[1]=v0.y; a[2]=v0.z; a[3]=v0.w;
        a[4]=v1.x; a[5]=v1.y; a[6]=v1.z; a[7]=v1.w;
      } else {
        #pragma unroll
        for (int j=0;j<8;j++) a[j]=0.f;
      }
      if constexpr (PRE == 1) {
        const float* bp = bpre + kc*32 + kq*8;
        float4 b0 = *(const float4*)bp;
        float4 b1 = *(const float4*)(bp+4);
        a[0]=frelu(a[0]+b0.x); a[1]=frelu(a[1]+b0.y);
        a[2]=frelu(a[2]+b0.z); a[3]=frelu(a[3]+b0.w);
        a[4]=frelu(a[4]+b1.x); a[5]=frelu(a[5]+b1.y);
        a[6]=frelu(a[6]+b1.z); a[7]=frelu(a[7]+b1.w);
      }
      union { short s[8]; bf16x8 v; } ph, pl;
      #pragma unroll
      for (int j=0;j<8;j++) {
        short h = f2bf(a[j]);
        ph.s[j] = h;
        pl.s[j] = f2bf(a[j] - bf2f(h));
      }
      int byte = (row<<6) | (kq<<4);
      byte ^= (row&7)<<4;
      *(bf16x8*)((char*)sAh + byte) = ph.v;
      *(bf16x8*)((char*)sAl + byte) = pl.v;
    }
    if (BN*4 >= 512 || tid < BN*4) {
      int idx = tid;
      int c = idx >> 2, kq = idx & 3;
      float a[8];
      if (COLS_REAL == BN || c < COLS_REAL) {
        const float* g = W + (size_t)c*K + kc*32 + kq*8;
        float4 v0 = *(const float4*)g;
        float4 v1 = *(const float4*)(g+4);
        a[0]=v0.x; a[1]=v0.y; a[2]=v0.z; a[3]=v0.w;
        a[4]=v1.x; a[5]=v1.y; a[6]=v1.z; a[7]=v1.w;
      } else {
        #pragma unroll
        for (int j=0;j<8;j++) a[j]=0.f;
      }
      union { short s[8]; bf16x8 v; } ph, pl;
      #pragma unroll
      for (int j=0;j<8;j++) {
        short h = f2bf(a[j]);
        ph.s[j] = h;
        pl.s[j] = f2bf(a[j] - bf2f(h));
      }
      int byte = (c<<6) | (kq<<4);
      byte ^= (c&7)<<4;
      *(bf16x8*)((char*)sWh + byte) = ph.v;
      *(bf16x8*)((char*)sWl + byte) = pl.v;
    }
    __syncthreads();
    bf16x8 fah[4], fal[4], fwh[4], fwl[4];
    #pragma unroll
    for (int rf=0; rf<4; ++rf) {
      int row = wr*64 + rf*16 + lrow;
      int byte = (row<<6) | (koct<<4);
      byte ^= (row&7)<<4;
      fah[rf] = *(const bf16x8*)((const char*)sAh + byte);
      fal[rf] = *(const bf16x8*)((const char*)sAl + byte);
    }
    #pragma unroll
    for (int cf=0; cf<4; ++cf) {
      int c = wc*64 + cf*16 + lrow;
      int byte = (c<<6) | (koct<<4);
      byte ^= (c&7)<<4;
      fwh[cf] = *(const bf16x8*)((const char*)sWh + byte);
      fwl[cf] = *(const bf16x8*)((const char*)sWl + byte);
    }
    #pragma unroll
    for (int rf=0; rf<4; ++rf)
      #pragma unroll
      for (int cf=0; cf<4; ++cf) {
        acc[rf][cf] = __builtin_amdgcn_mfma_f32_16x16x32_bf16(fah[rf], fwh[cf], acc[rf][cf], 0,0,0);
        acc[rf][cf] = __builtin_amdgcn_mfma_f32_16x16x32_bf16(fah[rf], fwl[cf], acc[rf][cf], 0,0,0);
        acc[rf][cf] = __builtin_amdgcn_mfma_f32_16x16x32_bf16(fal[rf], fwh[cf], acc[rf][cf], 0,0,0);
      }
  }
  const int crow = (l >> 4) * 4;
  float bpc[4];
  if constexpr (EPI==1 || EPI==2 || EPI==3) {
    #pragma unroll
    for (int cf=0; cf<4; ++cf) {
      int col = wc*64 + cf*16 + (l & 15);
      bpc[cf] = (COLS_REAL == BN || col < COLS_REAL) ? bpost[col] : 0.f;
    }
  }
  #pragma unroll
  for (int rf=0; rf<4; ++rf) {
    #pragma unroll
    for (int reg=0; reg<4; ++reg) {
      int row = wr*64 + rf*16 + crow + reg;
      int node = nb0 + row;
      if (node >= n) continue;
      float ds = 1.f;
      if constexpr (EPI==4 || EPI==5) ds = dscale[node];
      #pragma unroll
      for (int cf=0; cf<4; ++cf) {
        int col = wc*64 + cf*16 + (l & 15);
        if (COLS_REAL != BN && col >= COLS_REAL) continue;
        float v = acc[rf][cf][reg];
        if constexpr (EPI==1) v += bpc[cf];
        if constexpr (EPI==2) v = frelu(v + bpc[cf]);
        if constexpr (EPI==3) v = frelu(v + bpc[cf]) + A[(size_t)node*K + col];
        if constexpr (EPI==4) v *= ds;
        if constexpr (EPI==5) {
          v *= ds;
          ((__half*)Out)[((size_t)(col>>4)*n + node)*16 + (col&15)] = __float2half_rn(v);
        } else {
          Out[(size_t)node*COLS_REAL + col] = v;
        }
      }
    }
  }
}

// ---------- weight pre-split into LDS-image layout ----------
__global__ __launch_bounds__(256) void k_wsplit(const float* __restrict__ W2,
    const float* __restrict__ W3, const float* __restrict__ W4,
    const float* __restrict__ Wc1, short* __restrict__ whi, short* __restrict__ wlo)
{
  int idx = blockIdx.x*256 + threadIdx.x;
  if (idx >= 57344) return;
  const float* src; int e, c, k, cbase;
  if (idx < 8192){ src=W2; e=idx; c=e>>6; k=e&63; cbase=0; }
  else if (idx < 24576){ src=W3; e=idx-8192; c=e>>7; k=e&127; cbase=8192; }
  else if (idx < 40960){ src=W4; e=idx-24576; c=e>>7; k=e&127; cbase=24576; }
  else { src=Wc1; e=idx-40960; c=e>>7; k=e&127; cbase=40960; }
  float v = src[e];
  short h = f2bf(v);
  short lo = f2bf(v - bf2f(h));
  int byte = ((c<<6) | ((k&31)<<1)) ^ ((c&7)<<4);
  int pos = cbase + (k>>5)*4096 + (byte>>1);
  whi[pos] = h; wlo[pos] = lo;
}

// ---------- fused MLP mega-kernel: x -> h1..h4 -> tp1 = (h4@Wc1^T)*dinv (fp16, chunk-major) ----------
__global__ __launch_bounds__(256) void k_mega(const float* __restrict__ x,
    const float* __restrict__ W1, const float* __restrict__ b1,
    const float* __restrict__ b2, const float* __restrict__ b3,
    const float* __restrict__ b4, const short* __restrict__ whi,
    const short* __restrict__ wlo, const float* __restrict__ dinv,
    __half* __restrict__ tp1, int n)
{
  __shared__ __align__(16) short sWh[4096], sWl[4096];
  __shared__ __align__(16) short bAh[4096], bAl[4096];
  __shared__ __align__(16) short bBh[4096], bBl[4096];
  __shared__ float sx[160];
  __shared__ float sW1[320];
  __shared__ float sb1[64];
  const int tid = threadIdx.x;
  const int nb0 = blockIdx.x*32;

  if (tid < 160){ int row = tid/5, col = tid - row*5; int node = nb0 + row;
    sx[tid] = (node < n) ? x[(size_t)node*5 + col] : 0.f; }
  if (tid < 64) sb1[tid] = b1[tid];
  for (int i = tid; i < 320; i += 256) sW1[i] = W1[i];
  __syncthreads();

  {
    int row = tid >> 3, c0 = (tid & 7)*8;
    float xr[5];
    #pragma unroll
    for (int k=0;k<5;k++) xr[k] = sx[row*5+k];
    #pragma unroll
    for (int j=0;j<8;j++){
      int c = c0 + j;
      float a = sb1[c];
      #pragma unroll
      for (int k=0;k<5;k++) a = fmaf(xr[k], sW1[c*5+k], a);
      a = frelu(a);
      short h = f2bf(a), lo = f2bf(a - bf2f(h));
      int byte = ((c>>5)<<11) + ((((row<<6)|((c&31)<<1))) ^ ((row&7)<<4));
      *(short*)((char*)bAh + byte) = h;
      *(short*)((char*)bAl + byte) = lo;
    }
  }

  const int l = tid & 63, w = tid >> 6;
  const int wr = w >> 1, wc = w & 1;
  const int lrow = l & 15, koct = l >> 4;
  const int arow = wr*16 + lrow;
  const int abyteNoKc = ((arow<<6)|(koct<<4)) ^ ((arow&7)<<4);
  int wbyte[4];
  #pragma unroll
  for (int cf=0; cf<4; ++cf){
    int c = wc*64 + cf*16 + lrow;
    wbyte[cf] = ((c<<6)|(koct<<4)) ^ ((c&7)<<4);
  }
  f32x4 acc[4];
  float res[4][4];

  auto run_layer = [&](const short* inH, const short* inL, int woff, int nkc){
    #pragma unroll
    for (int cf=0; cf<4; ++cf) acc[cf] = (f32x4){0.f,0.f,0.f,0.f};
    for (int kc=0; kc<nkc; ++kc){
      __syncthreads();
      {
        const bf16x8* gh = (const bf16x8*)(whi + woff + kc*4096);
        const bf16x8* gl = (const bf16x8*)(wlo + woff + kc*4096);
        ((bf16x8*)sWh)[tid*2]   = gh[tid*2];
        ((bf16x8*)sWh)[tid*2+1] = gh[tid*2+1];
        ((bf16x8*)sWl)[tid*2]   = gl[tid*2];
        ((bf16x8*)sWl)[tid*2+1] = gl[tid*2+1];
      }
      __syncthreads();
      int ab = (kc<<11) + abyteNoKc;
      bf16x8 fah = *(const bf16x8*)((const char*)inH + ab);
      bf16x8 fal = *(const bf16x8*)((const char*)inL + ab);
      #pragma unroll
      for (int cf=0; cf<4; ++cf){
        bf16x8 fwh = *(const bf16x8*)((const char*)sWh + wbyte[cf]);
        bf16x8 fwl = *(const bf16x8*)((const char*)sWl + wbyte[cf]);
        acc[cf] = __builtin_amdgcn_mfma_f32_16x16x32_bf16(fah, fwh, acc[cf], 0,0,0);
        acc[cf] = __builtin_amdgcn_mfma_f32_16x16x32_bf16(fah, fwl, acc[cf], 0,0,0);
        acc[cf] = __builtin_amdgcn_mfma_f32_16x16x32_bf16(fal, fwh, acc[cf], 0,0,0);
      }
    }
  };
  auto store_buf = [&](short* outH, short* outL, int cf, int reg, float v){
    int row = wr*16 + koct*4 + reg;
    int col = wc*64 + cf*16 + lrow;
    short h = f2bf(v), lo = f2bf(v - bf2f(h));
    int byte = ((col>>5)<<11) + (((row<<6)|((col&31)<<1)) ^ ((row&7)<<4));
    *(short*)((char*)outH + byte) = h;
    *(short*)((char*)outL + byte) = lo;
  };

  run_layer(bAh, bAl, 0, 2);
  #pragma unroll
  for (int cf=0; cf<4; ++cf){
    float bb = b2[wc*64 + cf*16 + lrow];
    #pragma unroll
    for (int reg=0; reg<4; ++reg){
      float v = frelu(acc[cf][reg] + bb);
      res[cf][reg] = v;
      store_buf(bBh, bBl, cf, reg, v);
    }
  }
  run_layer(bBh, bBl, 8192, 4);
  #pragma unroll
  for (int cf=0; cf<4; ++cf){
    float bb = b3[wc*64 + cf*16 + lrow];
    #pragma unroll
    for (int reg=0; reg<4; ++reg){
      float v = frelu(acc[cf][reg] + bb) + res[cf][reg];
      res[cf][reg] = v;
      store_buf(bAh, bAl, cf, reg, v);
    }
  }
  run_layer(bAh, bAl, 24576, 4);
  #pragma unroll
  for (int cf=0; cf<4; ++cf){
    float bb = b4[wc*64 + cf*16 + lrow];
    #pragma unroll
    for (int reg=0; reg<4; ++reg){
      float v = frelu(acc[cf][reg] + bb) + res[cf][reg];
      store_buf(bBh, bBl, cf, reg, v);
    }
  }
  run_layer(bBh, bBl, 40960, 4);
  #pragma unroll
  for (int reg=0; reg<4; ++reg){
    int row = wr*16 + koct*4 + reg;
    int node = nb0 + row;
    float di = dinv[min(node, n-1)];
    #pragma unroll
    for (int cf=0; cf<4; ++cf){
      int col = wc*64 + cf*16 + lrow;
      if (node < n)
        tp1[((size_t)(col>>4)*n + node)*16 + (col&15)] = __float2half_rn(acc[cf][reg]*di);
    }
  }
}

// ---------- bucket sort of edges by dst (256 nodes / bucket) ----------
__global__ __launch_bounds__(512) void k_zero512(int* __restrict__ a, int m){
  int i = threadIdx.x; if (i<m) a[i]=0;
}
__global__ __launch_bounds__(512) void k_bhist(const int* __restrict__ dst,
    int* __restrict__ bcnt, int E, int nbuck){
  __shared__ int l[512];
  int tid = threadIdx.x;
  if (tid < nbuck) l[tid]=0;
  __syncthreads();
  for (int e = blockIdx.x*512 + tid; e < E; e += gridDim.x*512)
    atomicAdd(&l[((unsigned)dst[e])>>8], 1);
  __syncthreads();
  if (tid < nbuck && l[tid]) atomicAdd(&bcnt[tid], l[tid]);
}
__global__ __launch_bounds__(512) void k_bscan(const int* __restrict__ bcnt,
    int* __restrict__ bbase, int* __restrict__ bcur, int nbuck){
  __shared__ int sc[512];
  int tid = threadIdx.x;
  int v = (tid<nbuck) ? bcnt[tid] : 0;
  sc[tid]=v; __syncthreads();
  for (int off=1; off<512; off<<=1){
    int t = (tid>=off)? sc[tid-off] : 0;
    __syncthreads();
    sc[tid]+=t;
    __syncthreads();
  }
  if (tid<nbuck){ bbase[tid]=sc[tid]-v; bcur[tid]=sc[tid]-v; }
  if (tid==nbuck-1) bbase[nbuck]=sc[tid];
}
__global__ __launch_bounds__(512) void k_bscatter(const int* __restrict__ src,
    const int* __restrict__ dst, int* __restrict__ bcur,
    unsigned* __restrict__ sorted, int E, int nbuck)
{
  __shared__ int lcnt[512];
  __shared__ int lbase[512];
  int tid = threadIdx.x;
  if (tid < nbuck) lcnt[tid]=0;
  __syncthreads();
  int e0 = blockIdx.x*8192;
  int e1 = min(e0+8192, E);
  for (int e = e0+tid; e < e1; e += 512)
    atomicAdd(&lcnt[((unsigned)dst[e])>>8], 1);
  __syncthreads();
  if (tid < nbuck) lbase[tid] = lcnt[tid] ? atomicAdd(&bcur[tid], lcnt[tid]) : 0;
  __syncthreads();
  if (tid < nbuck) lcnt[tid]=0;
  __syncthreads();
  for (int e = e0+tid; e < e1; e += 512){
    int d = dst[e];
    int k = ((unsigned)d)>>8;
    int pos = lbase[k] + atomicAdd(&lcnt[k], 1);
    sorted[pos] = (((unsigned)src[e])<<8) | ((unsigned)d & 255u);
  }
}
__global__ __launch_bounds__(512) void k_finesort(unsigned* __restrict__ sorted,
    const int* __restrict__ bbase, int* __restrict__ cend,
    float* __restrict__ dinv, int n, int* __restrict__ fb)
{
  constexpr int CAP = 16384;
  __shared__ int lsorted[CAP];
  __shared__ int cnt[256], cur[256], sc[256];
  const int k = blockIdx.x;
  const int base = bbase[k], endb = bbase[k+1];
  const int m = endb - base;
  const int node0 = k<<8;
  const int tid = threadIdx.x;
  if (tid<256) cnt[tid]=0;
  __syncthreads();
  for (int i=tid; i<m; i+=512) atomicAdd(&cnt[sorted[base+i]&255u], 1);
  __syncthreads();
  int v=0;
  if (tid<256){ v=cnt[tid]; sc[tid]=v; }
  __syncthreads();
  for (int off=1; off<256; off<<=1){
    int t=0;
    if (tid>=off && tid<256) t=sc[tid-off];
    __syncthreads();
    if (tid<256) sc[tid]+=t;
    __syncthreads();
  }
  if (tid<256){
    cur[tid]=sc[tid]-v;
    int node = node0 + tid;
    if (node < n){
      cend[node] = base + sc[tid];
      dinv[node] = rsqrtf((float)v + 1.0f);
    }
  }
  __syncthreads();
  if (m <= CAP){
    for (int i=tid; i<m; i+=512){
      unsigned p = sorted[base+i];
      int pos = atomicAdd(&cur[p&255u], 1);
      lsorted[pos] = (int)(p>>8);
    }
    __syncthreads();
    for (int i=tid; i<m; i+=512) sorted[base+i] = (unsigned)lsorted[i];
  } else {
    for (int i=tid; i<m; i+=512) fb[base+i] = (int)sorted[base+i];
    __syncthreads();
    for (int i=tid; i<m; i+=512){
      unsigned p = (unsigned)fb[base+i];
      int pos = atomicAdd(&cur[p&255u], 1);
      sorted[base+pos] = p>>8;
    }
  }
}

// ---------- chunk-major gather aggregation, XCD-pinned ----------
// tpc[chunk][node][16ch] fp16: chunk slab = n*32 B contiguous (3.2 MB, fits
// 4 MB per-XCD L2). chunk = blockIdx&7 pins slab to XCD via round-robin.
// One node per wave; eg=l>>3 edge-group x ch=l&7 half2-slot; NT loads for
// streaming srcs, NT stores for out (protect slab residency).
__global__ __launch_bounds__(512) void k_aggc(const int* __restrict__ cend,
    const unsigned* __restrict__ srcs, const float* __restrict__ dinv,
    const __half* __restrict__ tp, float* __restrict__ out, int n)
{
  const int chunk = blockIdx.x & 7;
  const int node = (blockIdx.x >> 3)*8 + (threadIdx.x >> 6);
  if (node >= n) return;
  const int l = threadIdx.x & 63;
  const int eg = l >> 3, ch = l & 7;
  const __half2* tpc = (const __half2*)tp + (size_t)chunk*n*8;  // slab base
  const int beg = (node==0) ? 0 : cend[node-1];
  const int end = cend[node];
  float2 acc = {0.f, 0.f};
  const int iters = (end - beg + 7) >> 3;
  for (int i=0; i<iters; ++i){
    int e = beg + i*8 + eg;
    int ec = min(e, end-1);
    unsigned s = __builtin_nontemporal_load(srcs + ec);
    __half2 h = tpc[(size_t)s*8 + ch];
    float m = (e < end) ? 1.f : 0.f;
    acc.x = fmaf(__low2float(h), m, acc.x);
    acc.y = fmaf(__high2float(h), m, acc.y);
  }
  #pragma unroll
  for (int msk=8; msk<64; msk<<=1){
    acc.x += __shfl_xor(acc.x, msk, 64);
    acc.y += __shfl_xor(acc.y, msk, 64);
  }
  if (eg == 0){
    __half2 h = tpc[(size_t)node*8 + ch];   // self-loop term (slab-resident)
    acc.x += __low2float(h); acc.y += __high2float(h);
    float di = dinv[node];
    float2 r; r.x = acc.x*di; r.y = acc.y*di;
    double rb; __builtin_memcpy(&rb, &r, 8);
    __builtin_nontemporal_store(rb, (double*)(out + (size_t)node*128 + (chunk*8+ch)*2));
  }
}

extern "C" void kernel_launch(void* const* d_in, const int* in_sizes, int n_in,
                              void* d_out, int out_size, void* d_ws, size_t ws_size,
                              hipStream_t stream)
{
  const float* x   = (const float*)d_in[0];
  const int*   ei  = (const int*)d_in[1];
  const float *W1=(const float*)d_in[2],  *b1=(const float*)d_in[3];
  const float *W2=(const float*)d_in[4],  *b2=(const float*)d_in[5];
  const float *W3=(const float*)d_in[6],  *b3=(const float*)d_in[7];
  const float *W4=(const float*)d_in[8],  *b4=(const float*)d_in[9];
  const float *Wc1=(const float*)d_in[10],*bc1=(const float*)d_in[11];
  const float *Wc2=(const float*)d_in[12],*bc2=(const float*)d_in[13];
  const float *W5=(const float*)d_in[14], *b5=(const float*)d_in[15];
  float* out = (float*)d_out;

  const int n = in_sizes[0] / 5;
  const int E = in_sizes[1] / 2;
  const int* esrc = ei;
  const int* edst = ei + E;
  const int nbuck = (n + 255) >> 8;

  dim3 B256(256), B512(512);
  const int G256 = (n + 255)/256;
  const int G512 = (n + 511)/512;
  const int GAGG = 8 * ((n + 7)/8);

  // workspace layout (~117 MB)
  char* p = (char*)d_ws;
  float* hA    = (float*)p;           p += (size_t)n*128*4;
  float* hB    = (float*)p;           p += (size_t)n*128*4;
  float* dinv  = (float*)p;           p += (size_t)n*4;
  int*   cend  = (int*)p;             p += (size_t)n*4;
  unsigned* sortedp = (unsigned*)p;   p += (size_t)E*4;
  int*   bcnt  = (int*)p;             p += 512*4;
  int*   bbase = (int*)p;             p += 513*4;
  int*   bcur  = (int*)p;             p += 512*4;
  short* whi   = (short*)p;           p += 57344*2;
  short* wlo   = (short*)p;           p += 57344*2;

  // --- bucket-sorted CSR build (first: k_mega needs dinv) ---
  k_zero512<<<dim3(1), B512, 0, stream>>>(bcnt, nbuck);
  k_bhist<<<dim3(512), B512, 0, stream>>>(edst, bcnt, E, nbuck);
  k_bscan<<<dim3(1), B512, 0, stream>>>(bcnt, bbase, bcur, nbuck);
  k_bscatter<<<dim3((E + 8191)/8192), B512, 0, stream>>>(esrc, edst, bcur, sortedp, E, nbuck);
  k_finesort<<<dim3(nbuck), B512, 0, stream>>>(sortedp, bbase, cend, dinv, n, (int*)hA);

  // --- weight pre-split ---
  k_wsplit<<<dim3(224), B256, 0, stream>>>(W2, W3, W4, Wc1, whi, wlo);

  // --- fused MLP + conv1 transform: tp1(half, chunk-major) -> hA ---
  k_mega<<<dim3((n + 31)/32), B256, 0, stream>>>(x, W1, b1, b2, b3, b4,
                                                 whi, wlo, dinv, (__half*)hA, n);
  // --- agg1 -> hB ---
  k_aggc<<<dim3(GAGG), B512, 0, stream>>>(cend, sortedp, dinv, (const __half*)hA, hB, n);

  // --- conv2: tp2(half, chunk-major) = (relu(agg1+bc1) @ Wc2.T)*dinv -> hA ---
  k_mgemm<128,128,128,1,5,4,2><<<dim3(G256), B512, 0, stream>>>(hB, Wc2, bc1, nullptr, dinv, hA, n);
  // --- agg2 -> hB ---
  k_aggc<<<dim3(GAGG), B512, 0, stream>>>(cend, sortedp, dinv, (const __half*)hA, hB, n);

  // --- final: out = relu(agg2+bc2) @ W5.T + b5 ---
  k_mgemm<128,64,60,1,1,8,1><<<dim3(G512), B512, 0, stream>>>(hB, W5, bc2, b5, nullptr, out, n);
}

// Round 8
// 631.494 us; speedup vs baseline: 1.5937x; 1.5937x over previous
//
#include <hip/hip_runtime.h>
#include <hip/hip_fp16.h>

typedef __attribute__((ext_vector_type(8))) short bf16x8;
typedef __attribute__((ext_vector_type(4))) float f32x4;

__device__ __forceinline__ float frelu(float v){ return fmaxf(v, 0.f); }
__device__ __forceinline__ short f2bf(float f){
  unsigned u = __float_as_uint(f);
  unsigned r = (u + 0x7fffu + ((u>>16)&1u)) >> 16;
  return (short)r;
}
__device__ __forceinline__ float bf2f(short h){
  return __uint_as_float(((unsigned)(unsigned short)h) << 16);
}

// ---------- weight pre-split into LDS-image layout ----------
// images: W2 @0 (2 chunks), W3 @8192 (4), W4 @24576 (4), Wc1 @40960 (4);
// chunk = 128c x 32k = 4096 shorts, byte=((c<<6)|((k&31)<<1))^((c&7)<<4)
__global__ __launch_bounds__(256) void k_wsplit(const float* __restrict__ W2,
    const float* __restrict__ W3, const float* __restrict__ W4,
    const float* __restrict__ Wc1, short* __restrict__ whi, short* __restrict__ wlo)
{
  int idx = blockIdx.x*256 + threadIdx.x;
  if (idx >= 57344) return;
  const float* src; int e, c, k, cbase;
  if (idx < 8192){ src=W2; e=idx; c=e>>6; k=e&63; cbase=0; }
  else if (idx < 24576){ src=W3; e=idx-8192; c=e>>7; k=e&127; cbase=8192; }
  else if (idx < 40960){ src=W4; e=idx-24576; c=e>>7; k=e&127; cbase=24576; }
  else { src=Wc1; e=idx-40960; c=e>>7; k=e&127; cbase=40960; }
  float v = src[e];
  short h = f2bf(v);
  short lo = f2bf(v - bf2f(h));
  int byte = ((c<<6) | ((k&31)<<1)) ^ ((c&7)<<4);
  int pos = cbase + (k>>5)*4096 + (byte>>1);
  whi[pos] = h; wlo[pos] = lo;
}

// ---------- fused MLP mega-kernel: x -> h1..h4 -> tp1 = (h4@Wc1^T)*dinv (fp16, row-major) ----------
__global__ __launch_bounds__(256) void k_mega(const float* __restrict__ x,
    const float* __restrict__ W1, const float* __restrict__ b1,
    const float* __restrict__ b2, const float* __restrict__ b3,
    const float* __restrict__ b4, const short* __restrict__ whi,
    const short* __restrict__ wlo, const float* __restrict__ dinv,
    __half* __restrict__ tp1, int n)
{
  __shared__ __align__(16) short sWh[4096], sWl[4096];
  __shared__ __align__(16) short bAh[4096], bAl[4096];
  __shared__ __align__(16) short bBh[4096], bBl[4096];
  __shared__ float sx[160];
  __shared__ float sW1[320];
  __shared__ float sb1[64];
  const int tid = threadIdx.x;
  const int nb0 = blockIdx.x*32;

  if (tid < 160){ int row = tid/5, col = tid - row*5; int node = nb0 + row;
    sx[tid] = (node < n) ? x[(size_t)node*5 + col] : 0.f; }
  if (tid < 64) sb1[tid] = b1[tid];
  for (int i = tid; i < 320; i += 256) sW1[i] = W1[i];
  __syncthreads();

  {
    int row = tid >> 3, c0 = (tid & 7)*8;
    float xr[5];
    #pragma unroll
    for (int k=0;k<5;k++) xr[k] = sx[row*5+k];
    #pragma unroll
    for (int j=0;j<8;j++){
      int c = c0 + j;
      float a = sb1[c];
      #pragma unroll
      for (int k=0;k<5;k++) a = fmaf(xr[k], sW1[c*5+k], a);
      a = frelu(a);
      short h = f2bf(a), lo = f2bf(a - bf2f(h));
      int byte = ((c>>5)<<11) + ((((row<<6)|((c&31)<<1))) ^ ((row&7)<<4));
      *(short*)((char*)bAh + byte) = h;
      *(short*)((char*)bAl + byte) = lo;
    }
  }

  const int l = tid & 63, w = tid >> 6;
  const int wr = w >> 1, wc = w & 1;
  const int lrow = l & 15, koct = l >> 4;
  const int arow = wr*16 + lrow;
  const int abyteNoKc = ((arow<<6)|(koct<<4)) ^ ((arow&7)<<4);
  int wbyte[4];
  #pragma unroll
  for (int cf=0; cf<4; ++cf){
    int c = wc*64 + cf*16 + lrow;
    wbyte[cf] = ((c<<6)|(koct<<4)) ^ ((c&7)<<4);
  }
  f32x4 acc[4];
  float res[4][4];

  auto run_layer = [&](const short* inH, const short* inL, int woff, int nkc){
    #pragma unroll
    for (int cf=0; cf<4; ++cf) acc[cf] = (f32x4){0.f,0.f,0.f,0.f};
    for (int kc=0; kc<nkc; ++kc){
      __syncthreads();
      {
        const bf16x8* gh = (const bf16x8*)(whi + woff + kc*4096);
        const bf16x8* gl = (const bf16x8*)(wlo + woff + kc*4096);
        ((bf16x8*)sWh)[tid*2]   = gh[tid*2];
        ((bf16x8*)sWh)[tid*2+1] = gh[tid*2+1];
        ((bf16x8*)sWl)[tid*2]   = gl[tid*2];
        ((bf16x8*)sWl)[tid*2+1] = gl[tid*2+1];
      }
      __syncthreads();
      int ab = (kc<<11) + abyteNoKc;
      bf16x8 fah = *(const bf16x8*)((const char*)inH + ab);
      bf16x8 fal = *(const bf16x8*)((const char*)inL + ab);
      #pragma unroll
      for (int cf=0; cf<4; ++cf){
        bf16x8 fwh = *(const bf16x8*)((const char*)sWh + wbyte[cf]);
        bf16x8 fwl = *(const bf16x8*)((const char*)sWl + wbyte[cf]);
        acc[cf] = __builtin_amdgcn_mfma_f32_16x16x32_bf16(fah, fwh, acc[cf], 0,0,0);
        acc[cf] = __builtin_amdgcn_mfma_f32_16x16x32_bf16(fah, fwl, acc[cf], 0,0,0);
        acc[cf] = __builtin_amdgcn_mfma_f32_16x16x32_bf16(fal, fwh, acc[cf], 0,0,0);
      }
    }
  };
  auto store_buf = [&](short* outH, short* outL, int cf, int reg, float v){
    int row = wr*16 + koct*4 + reg;
    int col = wc*64 + cf*16 + lrow;
    short h = f2bf(v), lo = f2bf(v - bf2f(h));
    int byte = ((col>>5)<<11) + (((row<<6)|((col&31)<<1)) ^ ((row&7)<<4));
    *(short*)((char*)outH + byte) = h;
    *(short*)((char*)outL + byte) = lo;
  };

  run_layer(bAh, bAl, 0, 2);
  #pragma unroll
  for (int cf=0; cf<4; ++cf){
    float bb = b2[wc*64 + cf*16 + lrow];
    #pragma unroll
    for (int reg=0; reg<4; ++reg){
      float v = frelu(acc[cf][reg] + bb);
      res[cf][reg] = v;
      store_buf(bBh, bBl, cf, reg, v);
    }
  }
  run_layer(bBh, bBl, 8192, 4);
  #pragma unroll
  for (int cf=0; cf<4; ++cf){
    float bb = b3[wc*64 + cf*16 + lrow];
    #pragma unroll
    for (int reg=0; reg<4; ++reg){
      float v = frelu(acc[cf][reg] + bb) + res[cf][reg];
      res[cf][reg] = v;
      store_buf(bAh, bAl, cf, reg, v);
    }
  }
  run_layer(bAh, bAl, 24576, 4);
  #pragma unroll
  for (int cf=0; cf<4; ++cf){
    float bb = b4[wc*64 + cf*16 + lrow];
    #pragma unroll
    for (int reg=0; reg<4; ++reg){
      float v = frelu(acc[cf][reg] + bb) + res[cf][reg];
      store_buf(bBh, bBl, cf, reg, v);
    }
  }
  run_layer(bBh, bBl, 40960, 4);
  #pragma unroll
  for (int reg=0; reg<4; ++reg){
    int row = wr*16 + koct*4 + reg;
    int node = nb0 + row;
    float di = dinv[min(node, n-1)];
    #pragma unroll
    for (int cf=0; cf<4; ++cf){
      int col = wc*64 + cf*16 + lrow;
      if (node < n)
        tp1[(size_t)node*128 + col] = __float2half_rn(acc[cf][reg]*di);
    }
  }
}

// ---------- bucket sort of edges by dst (256 nodes / bucket) ----------
__global__ __launch_bounds__(512) void k_zero512(int* __restrict__ a, int m){
  int i = threadIdx.x; if (i<m) a[i]=0;
}
__global__ __launch_bounds__(512) void k_bhist(const int* __restrict__ dst,
    int* __restrict__ bcnt, int E, int nbuck){
  __shared__ int l[512];
  int tid = threadIdx.x;
  if (tid < nbuck) l[tid]=0;
  __syncthreads();
  for (int e = blockIdx.x*512 + tid; e < E; e += gridDim.x*512)
    atomicAdd(&l[((unsigned)dst[e])>>8], 1);
  __syncthreads();
  if (tid < nbuck && l[tid]) atomicAdd(&bcnt[tid], l[tid]);
}
__global__ __launch_bounds__(512) void k_bscan(const int* __restrict__ bcnt,
    int* __restrict__ bbase, int* __restrict__ bcur, int nbuck){
  __shared__ int sc[512];
  int tid = threadIdx.x;
  int v = (tid<nbuck) ? bcnt[tid] : 0;
  sc[tid]=v; __syncthreads();
  for (int off=1; off<512; off<<=1){
    int t = (tid>=off)? sc[tid-off] : 0;
    __syncthreads();
    sc[tid]+=t;
    __syncthreads();
  }
  if (tid<nbuck){ bbase[tid]=sc[tid]-v; bcur[tid]=sc[tid]-v; }
  if (tid==nbuck-1) bbase[nbuck]=sc[tid];
}
__global__ __launch_bounds__(512) void k_bscatter(const int* __restrict__ src,
    const int* __restrict__ dst, int* __restrict__ bcur,
    unsigned* __restrict__ sorted, int E, int nbuck)
{
  __shared__ int lcnt[512];
  __shared__ int lbase[512];
  int tid = threadIdx.x;
  if (tid < nbuck) lcnt[tid]=0;
  __syncthreads();
  int e0 = blockIdx.x*8192;
  int e1 = min(e0+8192, E);
  for (int e = e0+tid; e < e1; e += 512)
    atomicAdd(&lcnt[((unsigned)dst[e])>>8], 1);
  __syncthreads();
  if (tid < nbuck) lbase[tid] = lcnt[tid] ? atomicAdd(&bcur[tid], lcnt[tid]) : 0;
  __syncthreads();
  if (tid < nbuck) lcnt[tid]=0;
  __syncthreads();
  for (int e = e0+tid; e < e1; e += 512){
    int d = dst[e];
    int k = ((unsigned)d)>>8;
    int pos = lbase[k] + atomicAdd(&lcnt[k], 1);
    sorted[pos] = (((unsigned)src[e])<<8) | ((unsigned)d & 255u);
  }
}
__global__ __launch_bounds__(512) void k_finesort(unsigned* __restrict__ sorted,
    const int* __restrict__ bbase, int* __restrict__ cend,
    float* __restrict__ dinv, int n, int* __restrict__ fb)
{
  constexpr int CAP = 16384;
  __shared__ int lsorted[CAP];
  __shared__ int cnt[256], cur[256], sc[256];
  const int k = blockIdx.x;
  const int base = bbase[k], endb = bbase[k+1];
  const int m = endb - base;
  const int node0 = k<<8;
  const int tid = threadIdx.x;
  if (tid<256) cnt[tid]=0;
  __syncthreads();
  for (int i=tid; i<m; i+=512) atomicAdd(&cnt[sorted[base+i]&255u], 1);
  __syncthreads();
  int v=0;
  if (tid<256){ v=cnt[tid]; sc[tid]=v; }
  __syncthreads();
  for (int off=1; off<256; off<<=1){
    int t=0;
    if (tid>=off && tid<256) t=sc[tid-off];
    __syncthreads();
    if (tid<256) sc[tid]+=t;
    __syncthreads();
  }
  if (tid<256){
    cur[tid]=sc[tid]-v;
    int node = node0 + tid;
    if (node < n){
      cend[node] = base + sc[tid];
      dinv[node] = rsqrtf((float)v + 1.0f);
    }
  }
  __syncthreads();
  if (m <= CAP){
    for (int i=tid; i<m; i+=512){
      unsigned p = sorted[base+i];
      int pos = atomicAdd(&cur[p&255u], 1);
      lsorted[pos] = (int)(p>>8);
    }
    __syncthreads();
    for (int i=tid; i<m; i+=512) sorted[base+i] = (unsigned)lsorted[i];
  } else {
    for (int i=tid; i<m; i+=512) fb[base+i] = (int)sorted[base+i];
    __syncthreads();
    for (int i=tid; i<m; i+=512){
      unsigned p = (unsigned)fb[base+i];
      int pos = atomicAdd(&cur[p&255u], 1);
      sorted[base+pos] = p>>8;
    }
  }
}

// ---------- fused gather + GEMM ----------
// Phase 1 (gather, r4-proven row pattern): for each of the block's 128 nodes,
// A[node][:] = relu(dinv[node]*(tp[node]+sum_{s in N} tp[s]) + bpre), split to
// bf16 hi/lo directly into the LDS A-tile (4 resident k-chunks).
// Phase 2: standard split-bf16 MFMA over BN cols.
// EPI 5: v*dinv[node] -> fp16 row-major Out. EPI 1: v+bpost -> fp32 Out.
template<int BN, int COLS_REAL, int WCG, int EPI>
__global__ __launch_bounds__(512) void k_gagg(const __half* __restrict__ tp,
    const int* __restrict__ cend, const unsigned* __restrict__ srcs,
    const float* __restrict__ dinv, const float* __restrict__ bpre,
    const float* __restrict__ W, const float* __restrict__ bpost,
    void* __restrict__ Outv, int n)
{
  constexpr int WRG = 8/WCG;        // row wave-groups
  constexpr int RF  = 8/WRG;        // 16-row frags per wave
  __shared__ __align__(16) short sAh[16384], sAl[16384];  // [4 kc][128r][32k]
  __shared__ __align__(16) short sWh[BN*32], sWl[BN*32];
  const int tid = threadIdx.x;
  const int w = tid >> 6, l = tid & 63;
  const int nb0 = blockIdx.x*128;
  const __half2* tpp = (const __half2*)tp;

  // ---- phase 1: gather 128 rows (wave w owns rows w, w+8, ...) ----
  const float bcx = bpre[2*l], bcy = bpre[2*l+1];
  for (int i=0; i<16; ++i){
    const int r = w + (i<<3);
    const int node = nb0 + r;
    float2 acc = {0.f, 0.f};
    if (node < n){
      const int beg = (node==0) ? 0 : cend[node-1];
      const int end = cend[node];
      __half2 h = tpp[(size_t)node*64 + l];       // self-loop term
      acc.x = __low2float(h); acc.y = __high2float(h);
      int e = beg;
      for (; e+4<=end; e+=4){
        unsigned s0=srcs[e], s1=srcs[e+1], s2=srcs[e+2], s3=srcs[e+3];
        __half2 h0 = tpp[(size_t)s0*64 + l];
        __half2 h1 = tpp[(size_t)s1*64 + l];
        __half2 h2 = tpp[(size_t)s2*64 + l];
        __half2 h3 = tpp[(size_t)s3*64 + l];
        acc.x += (__low2float(h0)+__low2float(h1)) + (__low2float(h2)+__low2float(h3));
        acc.y += (__high2float(h0)+__high2float(h1)) + (__high2float(h2)+__high2float(h3));
      }
      for (; e<end; ++e){
        __half2 hh = tpp[(size_t)srcs[e]*64 + l];
        acc.x += __low2float(hh); acc.y += __high2float(hh);
      }
      const float di = dinv[node];
      acc.x = frelu(fmaf(acc.x, di, bcx));
      acc.y = frelu(fmaf(acc.y, di, bcy));
    }
    union { short s[2]; unsigned u; } ph, pl;
    ph.s[0] = f2bf(acc.x); pl.s[0] = f2bf(acc.x - bf2f(ph.s[0]));
    ph.s[1] = f2bf(acc.y); pl.s[1] = f2bf(acc.y - bf2f(ph.s[1]));
    const int k = l << 1;
    const int byte = ((k>>5)<<13) + ((((r<<6)|((k&31)<<1))) ^ ((r&7)<<4));
    *(unsigned*)((char*)sAh + byte) = ph.u;
    *(unsigned*)((char*)sAl + byte) = pl.u;
  }
  __syncthreads();

  // ---- phase 2: GEMM over resident A-tile ----
  const int wr = w % WRG, wc = w / WRG;
  const int lrow = l & 15, koct = l >> 4;
  f32x4 acc[RF][4];
  #pragma unroll
  for (int rf=0; rf<RF; ++rf)
    #pragma unroll
    for (int cf=0; cf<4; ++cf) acc[rf][cf] = (f32x4){0.f,0.f,0.f,0.f};
  int abyte[RF], wbyte[4];
  #pragma unroll
  for (int rf=0; rf<RF; ++rf){
    int arow = wr*(RF*16) + rf*16 + lrow;
    abyte[rf] = ((arow<<6)|(koct<<4)) ^ ((arow&7)<<4);
  }
  #pragma unroll
  for (int cf=0; cf<4; ++cf){
    int c = wc*64 + cf*16 + lrow;
    wbyte[cf] = ((c<<6)|(koct<<4)) ^ ((c&7)<<4);
  }
  for (int kc=0; kc<4; ++kc){
    if (kc) __syncthreads();
    if (BN*4 >= 512 || tid < BN*4){
      int c = tid >> 2, kq = tid & 3;
      float a[8];
      if (COLS_REAL == BN || c < COLS_REAL){
        const float* g = W + (size_t)c*128 + kc*32 + kq*8;
        float4 v0 = *(const float4*)g;
        float4 v1 = *(const float4*)(g+4);
        a[0]=v0.x; a[1]=v0.y; a[2]=v0.z; a[3]=v0.w;
        a[4]=v1.x; a[5]=v1.y; a[6]=v1.z; a[7]=v1.w;
      } else {
        #pragma unroll
        for (int j=0;j<8;j++) a[j]=0.f;
      }
      union { short s[8]; bf16x8 v; } ph, pl;
      #pragma unroll
      for (int j=0;j<8;j++){
        short h = f2bf(a[j]);
        ph.s[j] = h;
        pl.s[j] = f2bf(a[j] - bf2f(h));
      }
      int byte = ((c<<6)|(kq<<4)) ^ ((c&7)<<4);
      *(bf16x8*)((char*)sWh + byte) = ph.v;
      *(bf16x8*)((char*)sWl + byte) = pl.v;
    }
    __syncthreads();
    bf16x8 fah[RF], fal[RF], fwh[4], fwl[4];
    #pragma unroll
    for (int rf=0; rf<RF; ++rf){
      int ab = (kc<<13) + abyte[rf];
      fah[rf] = *(const bf16x8*)((const char*)sAh + ab);
      fal[rf] = *(const bf16x8*)((const char*)sAl + ab);
    }
    #pragma unroll
    for (int cf=0; cf<4; ++cf){
      fwh[cf] = *(const bf16x8*)((const char*)sWh + wbyte[cf]);
      fwl[cf] = *(const bf16x8*)((const char*)sWl + wbyte[cf]);
    }
    #pragma unroll
    for (int rf=0; rf<RF; ++rf)
      #pragma unroll
      for (int cf=0; cf<4; ++cf){
        acc[rf][cf] = __builtin_amdgcn_mfma_f32_16x16x32_bf16(fah[rf], fwh[cf], acc[rf][cf], 0,0,0);
        acc[rf][cf] = __builtin_amdgcn_mfma_f32_16x16x32_bf16(fah[rf], fwl[cf], acc[rf][cf], 0,0,0);
        acc[rf][cf] = __builtin_amdgcn_mfma_f32_16x16x32_bf16(fal[rf], fwh[cf], acc[rf][cf], 0,0,0);
      }
  }
  // ---- epilogue ----
  const int crow = koct*4;
  float bpc[4];
  if constexpr (EPI == 1){
    #pragma unroll
    for (int cf=0; cf<4; ++cf){
      int col = wc*64 + cf*16 + lrow;
      bpc[cf] = (COLS_REAL == BN || col < COLS_REAL) ? bpost[col] : 0.f;
    }
  }
  #pragma unroll
  for (int rf=0; rf<RF; ++rf){
    #pragma unroll
    for (int reg=0; reg<4; ++reg){
      int row = wr*(RF*16) + rf*16 + crow + reg;
      int node = nb0 + row;
      if (node >= n) continue;
      float ds = 1.f;
      if constexpr (EPI == 5) ds = dinv[node];
      #pragma unroll
      for (int cf=0; cf<4; ++cf){
        int col = wc*64 + cf*16 + lrow;
        if (COLS_REAL != BN && col >= COLS_REAL) continue;
        float v = acc[rf][cf][reg];
        if constexpr (EPI == 5){
          ((__half*)Outv)[(size_t)node*128 + col] = __float2half_rn(v*ds);
        } else {
          ((float*)Outv)[(size_t)node*COLS_REAL + col] = v + bpc[cf];
        }
      }
    }
  }
}

extern "C" void kernel_launch(void* const* d_in, const int* in_sizes, int n_in,
                              void* d_out, int out_size, void* d_ws, size_t ws_size,
                              hipStream_t stream)
{
  const float* x   = (const float*)d_in[0];
  const int*   ei  = (const int*)d_in[1];
  const float *W1=(const float*)d_in[2],  *b1=(const float*)d_in[3];
  const float *W2=(const float*)d_in[4],  *b2=(const float*)d_in[5];
  const float *W3=(const float*)d_in[6],  *b3=(const float*)d_in[7];
  const float *W4=(const float*)d_in[8],  *b4=(const float*)d_in[9];
  const float *Wc1=(const float*)d_in[10],*bc1=(const float*)d_in[11];
  const float *Wc2=(const float*)d_in[12],*bc2=(const float*)d_in[13];
  const float *W5=(const float*)d_in[14], *b5=(const float*)d_in[15];
  float* out = (float*)d_out;

  const int n = in_sizes[0] / 5;
  const int E = in_sizes[1] / 2;
  const int* esrc = ei;
  const int* edst = ei + E;
  const int nbuck = (n + 255) >> 8;

  dim3 B256(256), B512(512);
  const int G128 = (n + 127)/128;

  // workspace layout (~117 MB)
  char* p = (char*)d_ws;
  float* hA    = (float*)p;           p += (size_t)n*128*4;
  float* hB    = (float*)p;           p += (size_t)n*128*4;
  float* dinv  = (float*)p;           p += (size_t)n*4;
  int*   cend  = (int*)p;             p += (size_t)n*4;
  unsigned* sortedp = (unsigned*)p;   p += (size_t)E*4;
  int*   bcnt  = (int*)p;             p += 512*4;
  int*   bbase = (int*)p;             p += 513*4;
  int*   bcur  = (int*)p;             p += 512*4;
  short* whi   = (short*)p;           p += 57344*2;
  short* wlo   = (short*)p;           p += 57344*2;

  // --- bucket-sorted CSR build (k_mega needs dinv) ---
  k_zero512<<<dim3(1), B512, 0, stream>>>(bcnt, nbuck);
  k_bhist<<<dim3(512), B512, 0, stream>>>(edst, bcnt, E, nbuck);
  k_bscan<<<dim3(1), B512, 0, stream>>>(bcnt, bbase, bcur, nbuck);
  k_bscatter<<<dim3((E + 8191)/8192), B512, 0, stream>>>(esrc, edst, bcur, sortedp, E, nbuck);
  k_finesort<<<dim3(nbuck), B512, 0, stream>>>(sortedp, bbase, cend, dinv, n, (int*)hA);

  // --- weight pre-split ---
  k_wsplit<<<dim3(224), B256, 0, stream>>>(W2, W3, W4, Wc1, whi, wlo);

  // --- fused MLP + conv1 transform: tp1(half, row-major) -> hA ---
  k_mega<<<dim3((n + 31)/32), B256, 0, stream>>>(x, W1, b1, b2, b3, b4,
                                                 whi, wlo, dinv, (__half*)hA, n);

  // --- fused agg1 + conv2 GEMM: tp2(half) = (relu(agg(tp1)+bc1)@Wc2^T)*dinv -> hB ---
  k_gagg<128,128,2,5><<<dim3(G128), B512, 0, stream>>>((const __half*)hA, cend, sortedp,
      dinv, bc1, Wc2, nullptr, hB, n);

  // --- fused agg2 + W5 GEMM: out = relu(agg(tp2)+bc2)@W5^T + b5 ---
  k_gagg<64,60,1,1><<<dim3(G128), B512, 0, stream>>>((const __half*)hB, cend, sortedp,
      dinv, bc2, W5, b5, out, n);
}

// Round 9
// 448.967 us; speedup vs baseline: 2.2416x; 1.4066x over previous
//
#include <hip/hip_runtime.h>
#include <hip/hip_fp16.h>

typedef __attribute__((ext_vector_type(8))) short bf16x8;
typedef __attribute__((ext_vector_type(4))) float f32x4;

__device__ __forceinline__ float frelu(float v){ return fmaxf(v, 0.f); }
__device__ __forceinline__ short f2bf(float f){
  unsigned u = __float_as_uint(f);
  unsigned r = (u + 0x7fffu + ((u>>16)&1u)) >> 16;
  return (short)r;
}
__device__ __forceinline__ float bf2f(short h){
  return __uint_as_float(((unsigned)(unsigned short)h) << 16);
}
__device__ __forceinline__ float4 addh4(float4 a, uint2 v){
  union { unsigned u; __half2 h; } p0, p1;
  p0.u = v.x; p1.u = v.y;
  a.x += __low2float(p0.h); a.y += __high2float(p0.h);
  a.z += __low2float(p1.h); a.w += __high2float(p1.h);
  return a;
}

// ---------- MFMA split-bf16 GEMM: Out = EPI( PRE(A) @ W.T ) ----------
// PRE: 0 id, 1 relu(a + bpre[k])
// EPI: 1 +bpost, 2 relu(+bpost), 3 relu(+bpost)+A[node][col] (K==BN),
//      4 *dscale[node] (fp32 out), 5 *dscale[node] -> fp16 row-major out
template<int K, int BN, int COLS_REAL, int PRE, int EPI, int WRG, int WCG>
__global__ __launch_bounds__(512) void k_mgemm(const float* __restrict__ A,
    const float* __restrict__ W, const float* __restrict__ bpre,
    const float* __restrict__ bpost, const float* __restrict__ dscale,
    float* __restrict__ Out, int n)
{
  constexpr int BM = WRG*64;
  __shared__ __align__(16) short sAh[BM*32];
  __shared__ __align__(16) short sAl[BM*32];
  __shared__ __align__(16) short sWh[BN*32];
  __shared__ __align__(16) short sWl[BN*32];

  const int tid = threadIdx.x;
  const int nb0 = blockIdx.x * BM;
  const int l = tid & 63;
  const int w = tid >> 6;
  const int wr = w % WRG;
  const int wc = w / WRG;
  const int lrow = l & 15;
  const int koct = l >> 4;

  f32x4 acc[4][4];
  #pragma unroll
  for (int i=0;i<4;i++)
    #pragma unroll
    for (int j=0;j<4;j++) acc[i][j] = (f32x4){0.f,0.f,0.f,0.f};

  for (int kc = 0; kc < K/32; ++kc) {
    if (kc) __syncthreads();
    #pragma unroll
    for (int t = 0; t < BM/128; ++t) {
      int idx = tid + t*512;
      int row = idx >> 2, kq = idx & 3;
      int node = nb0 + row;
      float a[8];
      if (node < n) {
        const float* g = A + (size_t)node*K + kc*32 + kq*8;
        float4 v0 = *(const float4*)g;
        float4 v1 = *(const float4*)(g+4);
        a[0]=v0.x; a[1]=v0.y; a[2]=v0.z; a[3]=v0.w;
        a[4]=v1.x; a[5]=v1.y; a[6]=v1.z; a[7]=v1.w;
      } else {
        #pragma unroll
        for (int j=0;j<8;j++) a[j]=0.f;
      }
      if constexpr (PRE == 1) {
        const float* bp = bpre + kc*32 + kq*8;
        float4 b0 = *(const float4*)bp;
        float4 b1 = *(const float4*)(bp+4);
        a[0]=frelu(a[0]+b0.x); a[1]=frelu(a[1]+b0.y);
        a[2]=frelu(a[2]+b0.z); a[3]=frelu(a[3]+b0.w);
        a[4]=frelu(a[4]+b1.x); a[5]=frelu(a[5]+b1.y);
        a[6]=frelu(a[6]+b1.z); a[7]=frelu(a[7]+b1.w);
      }
      union { short s[8]; bf16x8 v; } ph, pl;
      #pragma unroll
      for (int j=0;j<8;j++) {
        short h = f2bf(a[j]);
        ph.s[j] = h;
        pl.s[j] = f2bf(a[j] - bf2f(h));
      }
      int byte = (row<<6) | (kq<<4);
      byte ^= (row&7)<<4;
      *(bf16x8*)((char*)sAh + byte) = ph.v;
      *(bf16x8*)((char*)sAl + byte) = pl.v;
    }
    if (BN*4 >= 512 || tid < BN*4) {
      int idx = tid;
      int c = idx >> 2, kq = idx & 3;
      float a[8];
      if (COLS_REAL == BN || c < COLS_REAL) {
        const float* g = W + (size_t)c*K + kc*32 + kq*8;
        float4 v0 = *(const float4*)g;
        float4 v1 = *(const float4*)(g+4);
        a[0]=v0.x; a[1]=v0.y; a[2]=v0.z; a[3]=v0.w;
        a[4]=v1.x; a[5]=v1.y; a[6]=v1.z; a[7]=v1.w;
      } else {
        #pragma unroll
        for (int j=0;j<8;j++) a[j]=0.f;
      }
      union { short s[8]; bf16x8 v; } ph, pl;
      #pragma unroll
      for (int j=0;j<8;j++) {
        short h = f2bf(a[j]);
        ph.s[j] = h;
        pl.s[j] = f2bf(a[j] - bf2f(h));
      }
      int byte = (c<<6) | (kq<<4);
      byte ^= (c&7)<<4;
      *(bf16x8*)((char*)sWh + byte) = ph.v;
      *(bf16x8*)((char*)sWl + byte) = pl.v;
    }
    __syncthreads();
    bf16x8 fah[4], fal[4], fwh[4], fwl[4];
    #pragma unroll
    for (int rf=0; rf<4; ++rf) {
      int row = wr*64 + rf*16 + lrow;
      int byte = (row<<6) | (koct<<4);
      byte ^= (row&7)<<4;
      fah[rf] = *(const bf16x8*)((const char*)sAh + byte);
      fal[rf] = *(const bf16x8*)((const char*)sAl + byte);
    }
    #pragma unroll
    for (int cf=0; cf<4; ++cf) {
      int c = wc*64 + cf*16 + lrow;
      int byte = (c<<6) | (koct<<4);
      byte ^= (c&7)<<4;
      fwh[cf] = *(const bf16x8*)((const char*)sWh + byte);
      fwl[cf] = *(const bf16x8*)((const char*)sWl + byte);
    }
    #pragma unroll
    for (int rf=0; rf<4; ++rf)
      #pragma unroll
      for (int cf=0; cf<4; ++cf) {
        acc[rf][cf] = __builtin_amdgcn_mfma_f32_16x16x32_bf16(fah[rf], fwh[cf], acc[rf][cf], 0,0,0);
        acc[rf][cf] = __builtin_amdgcn_mfma_f32_16x16x32_bf16(fah[rf], fwl[cf], acc[rf][cf], 0,0,0);
        acc[rf][cf] = __builtin_amdgcn_mfma_f32_16x16x32_bf16(fal[rf], fwh[cf], acc[rf][cf], 0,0,0);
      }
  }
  const int crow = (l >> 4) * 4;
  float bpc[4];
  if constexpr (EPI==1 || EPI==2 || EPI==3) {
    #pragma unroll
    for (int cf=0; cf<4; ++cf) {
      int col = wc*64 + cf*16 + (l & 15);
      bpc[cf] = (COLS_REAL == BN || col < COLS_REAL) ? bpost[col] : 0.f;
    }
  }
  #pragma unroll
  for (int rf=0; rf<4; ++rf) {
    #pragma unroll
    for (int reg=0; reg<4; ++reg) {
      int row = wr*64 + rf*16 + crow + reg;
      int node = nb0 + row;
      if (node >= n) continue;
      float ds = 1.f;
      if constexpr (EPI==4 || EPI==5) ds = dscale[node];
      #pragma unroll
      for (int cf=0; cf<4; ++cf) {
        int col = wc*64 + cf*16 + (l & 15);
        if (COLS_REAL != BN && col >= COLS_REAL) continue;
        float v = acc[rf][cf][reg];
        if constexpr (EPI==1) v += bpc[cf];
        if constexpr (EPI==2) v = frelu(v + bpc[cf]);
        if constexpr (EPI==3) v = frelu(v + bpc[cf]) + A[(size_t)node*K + col];
        if constexpr (EPI==4) v *= ds;
        if constexpr (EPI==5) {
          v *= ds;
          ((__half*)Out)[(size_t)node*COLS_REAL + col] = __float2half_rn(v);
        } else {
          Out[(size_t)node*COLS_REAL + col] = v;
        }
      }
    }
  }
}

// ---------- weight pre-split into LDS-image layout (+ zero bcnt in block 0) ----------
__global__ __launch_bounds__(256) void k_wsplit(const float* __restrict__ W2,
    const float* __restrict__ W3, const float* __restrict__ W4,
    const float* __restrict__ Wc1, short* __restrict__ whi, short* __restrict__ wlo,
    int* __restrict__ bcnt)
{
  if (blockIdx.x == 0){
    bcnt[threadIdx.x] = 0;
    bcnt[threadIdx.x + 256] = 0;
  }
  int idx = blockIdx.x*256 + threadIdx.x;
  if (idx >= 57344) return;
  const float* src; int e, c, k, cbase;
  if (idx < 8192){ src=W2; e=idx; c=e>>6; k=e&63; cbase=0; }
  else if (idx < 24576){ src=W3; e=idx-8192; c=e>>7; k=e&127; cbase=8192; }
  else if (idx < 40960){ src=W4; e=idx-24576; c=e>>7; k=e&127; cbase=24576; }
  else { src=Wc1; e=idx-40960; c=e>>7; k=e&127; cbase=40960; }
  float v = src[e];
  short h = f2bf(v);
  short lo = f2bf(v - bf2f(h));
  int byte = ((c<<6) | ((k&31)<<1)) ^ ((c&7)<<4);
  int pos = cbase + (k>>5)*4096 + (byte>>1);
  whi[pos] = h; wlo[pos] = lo;
}

// ---------- fused MLP mega-kernel: x -> h1..h4 -> tp1 = (h4@Wc1^T)*dinv (fp16, row-major) ----------
__global__ __launch_bounds__(256) void k_mega(const float* __restrict__ x,
    const float* __restrict__ W1, const float* __restrict__ b1,
    const float* __restrict__ b2, const float* __restrict__ b3,
    const float* __restrict__ b4, const short* __restrict__ whi,
    const short* __restrict__ wlo, const float* __restrict__ dinv,
    __half* __restrict__ tp1, int n)
{
  __shared__ __align__(16) short sWh[4096], sWl[4096];
  __shared__ __align__(16) short bAh[4096], bAl[4096];
  __shared__ __align__(16) short bBh[4096], bBl[4096];
  __shared__ float sx[160];
  __shared__ float sW1[320];
  __shared__ float sb1[64];
  const int tid = threadIdx.x;
  const int nb0 = blockIdx.x*32;

  if (tid < 160){ int row = tid/5, col = tid - row*5; int node = nb0 + row;
    sx[tid] = (node < n) ? x[(size_t)node*5 + col] : 0.f; }
  if (tid < 64) sb1[tid] = b1[tid];
  for (int i = tid; i < 320; i += 256) sW1[i] = W1[i];
  __syncthreads();

  {
    int row = tid >> 3, c0 = (tid & 7)*8;
    float xr[5];
    #pragma unroll
    for (int k=0;k<5;k++) xr[k] = sx[row*5+k];
    #pragma unroll
    for (int j=0;j<8;j++){
      int c = c0 + j;
      float a = sb1[c];
      #pragma unroll
      for (int k=0;k<5;k++) a = fmaf(xr[k], sW1[c*5+k], a);
      a = frelu(a);
      short h = f2bf(a), lo = f2bf(a - bf2f(h));
      int byte = ((c>>5)<<11) + ((((row<<6)|((c&31)<<1))) ^ ((row&7)<<4));
      *(short*)((char*)bAh + byte) = h;
      *(short*)((char*)bAl + byte) = lo;
    }
  }

  const int l = tid & 63, w = tid >> 6;
  const int wr = w >> 1, wc = w & 1;
  const int lrow = l & 15, koct = l >> 4;
  const int arow = wr*16 + lrow;
  const int abyteNoKc = ((arow<<6)|(koct<<4)) ^ ((arow&7)<<4);
  int wbyte[4];
  #pragma unroll
  for (int cf=0; cf<4; ++cf){
    int c = wc*64 + cf*16 + lrow;
    wbyte[cf] = ((c<<6)|(koct<<4)) ^ ((c&7)<<4);
  }
  f32x4 acc[4];
  float res[4][4];

  auto run_layer = [&](const short* inH, const short* inL, int woff, int nkc){
    #pragma unroll
    for (int cf=0; cf<4; ++cf) acc[cf] = (f32x4){0.f,0.f,0.f,0.f};
    for (int kc=0; kc<nkc; ++kc){
      __syncthreads();
      {
        const bf16x8* gh = (const bf16x8*)(whi + woff + kc*4096);
        const bf16x8* gl = (const bf16x8*)(wlo + woff + kc*4096);
        ((bf16x8*)sWh)[tid*2]   = gh[tid*2];
        ((bf16x8*)sWh)[tid*2+1] = gh[tid*2+1];
        ((bf16x8*)sWl)[tid*2]   = gl[tid*2];
        ((bf16x8*)sWl)[tid*2+1] = gl[tid*2+1];
      }
      __syncthreads();
      int ab = (kc<<11) + abyteNoKc;
      bf16x8 fah = *(const bf16x8*)((const char*)inH + ab);
      bf16x8 fal = *(const bf16x8*)((const char*)inL + ab);
      #pragma unroll
      for (int cf=0; cf<4; ++cf){
        bf16x8 fwh = *(const bf16x8*)((const char*)sWh + wbyte[cf]);
        bf16x8 fwl = *(const bf16x8*)((const char*)sWl + wbyte[cf]);
        acc[cf] = __builtin_amdgcn_mfma_f32_16x16x32_bf16(fah, fwh, acc[cf], 0,0,0);
        acc[cf] = __builtin_amdgcn_mfma_f32_16x16x32_bf16(fah, fwl, acc[cf], 0,0,0);
        acc[cf] = __builtin_amdgcn_mfma_f32_16x16x32_bf16(fal, fwh, acc[cf], 0,0,0);
      }
    }
  };
  auto store_buf = [&](short* outH, short* outL, int cf, int reg, float v){
    int row = wr*16 + koct*4 + reg;
    int col = wc*64 + cf*16 + lrow;
    short h = f2bf(v), lo = f2bf(v - bf2f(h));
    int byte = ((col>>5)<<11) + (((row<<6)|((col&31)<<1)) ^ ((row&7)<<4));
    *(short*)((char*)outH + byte) = h;
    *(short*)((char*)outL + byte) = lo;
  };

  run_layer(bAh, bAl, 0, 2);
  #pragma unroll
  for (int cf=0; cf<4; ++cf){
    float bb = b2[wc*64 + cf*16 + lrow];
    #pragma unroll
    for (int reg=0; reg<4; ++reg){
      float v = frelu(acc[cf][reg] + bb);
      res[cf][reg] = v;
      store_buf(bBh, bBl, cf, reg, v);
    }
  }
  run_layer(bBh, bBl, 8192, 4);
  #pragma unroll
  for (int cf=0; cf<4; ++cf){
    float bb = b3[wc*64 + cf*16 + lrow];
    #pragma unroll
    for (int reg=0; reg<4; ++reg){
      float v = frelu(acc[cf][reg] + bb) + res[cf][reg];
      res[cf][reg] = v;
      store_buf(bAh, bAl, cf, reg, v);
    }
  }
  run_layer(bAh, bAl, 24576, 4);
  #pragma unroll
  for (int cf=0; cf<4; ++cf){
    float bb = b4[wc*64 + cf*16 + lrow];
    #pragma unroll
    for (int reg=0; reg<4; ++reg){
      float v = frelu(acc[cf][reg] + bb) + res[cf][reg];
      store_buf(bBh, bBl, cf, reg, v);
    }
  }
  run_layer(bBh, bBl, 40960, 4);
  #pragma unroll
  for (int reg=0; reg<4; ++reg){
    int row = wr*16 + koct*4 + reg;
    int node = nb0 + row;
    float di = dinv[min(node, n-1)];
    #pragma unroll
    for (int cf=0; cf<4; ++cf){
      int col = wc*64 + cf*16 + lrow;
      if (node < n)
        tp1[(size_t)node*128 + col] = __float2half_rn(acc[cf][reg]*di);
    }
  }
}

// ---------- bucket sort of edges by dst (256 nodes / bucket) ----------
__global__ __launch_bounds__(512) void k_bhist(const int* __restrict__ dst,
    int* __restrict__ bcnt, int E, int nbuck){
  __shared__ int l[512];
  int tid = threadIdx.x;
  if (tid < nbuck) l[tid]=0;
  __syncthreads();
  for (int e = blockIdx.x*512 + tid; e < E; e += gridDim.x*512)
    atomicAdd(&l[((unsigned)dst[e])>>8], 1);
  __syncthreads();
  if (tid < nbuck && l[tid]) atomicAdd(&bcnt[tid], l[tid]);
}
__global__ __launch_bounds__(512) void k_bscan(const int* __restrict__ bcnt,
    int* __restrict__ bbase, int* __restrict__ bcur, int nbuck){
  __shared__ int sc[512];
  int tid = threadIdx.x;
  int v = (tid<nbuck) ? bcnt[tid] : 0;
  sc[tid]=v; __syncthreads();
  for (int off=1; off<512; off<<=1){
    int t = (tid>=off)? sc[tid-off] : 0;
    __syncthreads();
    sc[tid]+=t;
    __syncthreads();
  }
  if (tid<nbuck){ bbase[tid]=sc[tid]-v; bcur[tid]=sc[tid]-v; }
  if (tid==nbuck-1) bbase[nbuck]=sc[tid];
}
__global__ __launch_bounds__(512) void k_bscatter(const int* __restrict__ src,
    const int* __restrict__ dst, int* __restrict__ bcur,
    unsigned* __restrict__ sorted, int E, int nbuck)
{
  __shared__ int lcnt[512];
  __shared__ int lbase[512];
  int tid = threadIdx.x;
  if (tid < nbuck) lcnt[tid]=0;
  __syncthreads();
  int e0 = blockIdx.x*8192;
  int e1 = min(e0+8192, E);
  for (int e = e0+tid; e < e1; e += 512)
    atomicAdd(&lcnt[((unsigned)dst[e])>>8], 1);
  __syncthreads();
  if (tid < nbuck) lbase[tid] = lcnt[tid] ? atomicAdd(&bcur[tid], lcnt[tid]) : 0;
  __syncthreads();
  if (tid < nbuck) lcnt[tid]=0;
  __syncthreads();
  for (int e = e0+tid; e < e1; e += 512){
    int d = dst[e];
    int k = ((unsigned)d)>>8;
    int pos = lbase[k] + atomicAdd(&lcnt[k], 1);
    sorted[pos] = (((unsigned)src[e])<<8) | ((unsigned)d & 255u);
  }
}
__global__ __launch_bounds__(512) void k_finesort(unsigned* __restrict__ sorted,
    const int* __restrict__ bbase, int* __restrict__ cend,
    float* __restrict__ dinv, int n, int* __restrict__ fb)
{
  constexpr int CAP = 16384;
  __shared__ int lsorted[CAP];
  __shared__ int cnt[256], cur[256], sc[256];
  const int k = blockIdx.x;
  const int base = bbase[k], endb = bbase[k+1];
  const int m = endb - base;
  const int node0 = k<<8;
  const int tid = threadIdx.x;
  if (tid<256) cnt[tid]=0;
  __syncthreads();
  for (int i=tid; i<m; i+=512) atomicAdd(&cnt[sorted[base+i]&255u], 1);
  __syncthreads();
  int v=0;
  if (tid<256){ v=cnt[tid]; sc[tid]=v; }
  __syncthreads();
  for (int off=1; off<256; off<<=1){
    int t=0;
    if (tid>=off && tid<256) t=sc[tid-off];
    __syncthreads();
    if (tid<256) sc[tid]+=t;
    __syncthreads();
  }
  if (tid<256){
    cur[tid]=sc[tid]-v;
    int node = node0 + tid;
    if (node < n){
      cend[node] = base + sc[tid];
      dinv[node] = rsqrtf((float)v + 1.0f);
    }
  }
  __syncthreads();
  if (m <= CAP){
    for (int i=tid; i<m; i+=512){
      unsigned p = sorted[base+i];
      int pos = atomicAdd(&cur[p&255u], 1);
      lsorted[pos] = (int)(p>>8);
    }
    __syncthreads();
    for (int i=tid; i<m; i+=512) sorted[base+i] = (unsigned)lsorted[i];
  } else {
    for (int i=tid; i<m; i+=512) fb[base+i] = (int)sorted[base+i];
    __syncthreads();
    for (int i=tid; i<m; i+=512){
      unsigned p = (unsigned)fb[base+i];
      int pos = atomicAdd(&cur[p&255u], 1);
      sorted[base+pos] = p>>8;
    }
  }
}

// ---------- gather aggregation: half-wave per edge, 8 B/lane ----------
// out[d] = dinv[d] * (tp[d] + sum_{s in N(d)} tp[s]); one wave per node;
// sub-wave (32 lanes x 8 B = 256 B row) per edge, 2 edges/inst, 4-deep unroll.
__global__ __launch_bounds__(256) void k_agg(const int* __restrict__ cend,
    const unsigned* __restrict__ srcs, const float* __restrict__ dinv,
    const __half* __restrict__ tp, float* __restrict__ out, int n)
{
  int node = blockIdx.x*4 + (threadIdx.x>>6);
  if (node >= n) return;
  const int lane = threadIdx.x & 63;
  const int sub = lane >> 5, li = lane & 31;
  const uint2* tpq = (const uint2*)tp;   // row = 32 x 8 B
  int beg = (node==0) ? 0 : cend[node-1];
  int end = cend[node];
  float4 acc = {0.f,0.f,0.f,0.f};
  int e = beg + sub;
  for (; e + 6 < end; e += 8){
    unsigned s0 = __builtin_nontemporal_load(srcs + e);
    unsigned s1 = __builtin_nontemporal_load(srcs + e + 2);
    unsigned s2 = __builtin_nontemporal_load(srcs + e + 4);
    unsigned s3 = __builtin_nontemporal_load(srcs + e + 6);
    uint2 v0 = tpq[(size_t)s0*32 + li];
    uint2 v1 = tpq[(size_t)s1*32 + li];
    uint2 v2 = tpq[(size_t)s2*32 + li];
    uint2 v3 = tpq[(size_t)s3*32 + li];
    acc = addh4(acc, v0);
    acc = addh4(acc, v1);
    acc = addh4(acc, v2);
    acc = addh4(acc, v3);
  }
  for (; e < end; e += 2){
    unsigned s = __builtin_nontemporal_load(srcs + e);
    uint2 v = tpq[(size_t)s*32 + li];
    acc = addh4(acc, v);
  }
  acc.x += __shfl_xor(acc.x, 32, 64);
  acc.y += __shfl_xor(acc.y, 32, 64);
  acc.z += __shfl_xor(acc.z, 32, 64);
  acc.w += __shfl_xor(acc.w, 32, 64);
  if (sub == 0){
    uint2 v = tpq[(size_t)node*32 + li];   // self-loop term
    acc = addh4(acc, v);
    float di = dinv[node];
    float4 r = {acc.x*di, acc.y*di, acc.z*di, acc.w*di};
    *(float4*)(out + (size_t)node*128 + li*4) = r;
  }
}

extern "C" void kernel_launch(void* const* d_in, const int* in_sizes, int n_in,
                              void* d_out, int out_size, void* d_ws, size_t ws_size,
                              hipStream_t stream)
{
  const float* x   = (const float*)d_in[0];
  const int*   ei  = (const int*)d_in[1];
  const float *W1=(const float*)d_in[2],  *b1=(const float*)d_in[3];
  const float *W2=(const float*)d_in[4],  *b2=(const float*)d_in[5];
  const float *W3=(const float*)d_in[6],  *b3=(const float*)d_in[7];
  const float *W4=(const float*)d_in[8],  *b4=(const float*)d_in[9];
  const float *Wc1=(const float*)d_in[10],*bc1=(const float*)d_in[11];
  const float *Wc2=(const float*)d_in[12],*bc2=(const float*)d_in[13];
  const float *W5=(const float*)d_in[14], *b5=(const float*)d_in[15];
  float* out = (float*)d_out;

  const int n = in_sizes[0] / 5;
  const int E = in_sizes[1] / 2;
  const int* esrc = ei;
  const int* edst = ei + E;
  const int nbuck = (n + 255) >> 8;

  dim3 B256(256), B512(512);
  const int G256 = (n + 255)/256;
  const int G512 = (n + 511)/512;

  // workspace layout (~117 MB)
  char* p = (char*)d_ws;
  float* hA    = (float*)p;           p += (size_t)n*128*4;
  float* hB    = (float*)p;           p += (size_t)n*128*4;
  float* dinv  = (float*)p;           p += (size_t)n*4;
  int*   cend  = (int*)p;             p += (size_t)n*4;
  unsigned* sortedp = (unsigned*)p;   p += (size_t)E*4;
  int*   bcnt  = (int*)p;             p += 512*4;
  int*   bbase = (int*)p;             p += 513*4;
  int*   bcur  = (int*)p;             p += 512*4;
  short* whi   = (short*)p;           p += 57344*2;
  short* wlo   = (short*)p;           p += 57344*2;

  // --- weight pre-split (block 0 zeroes bcnt) ---
  k_wsplit<<<dim3(224), B256, 0, stream>>>(W2, W3, W4, Wc1, whi, wlo, bcnt);

  // --- bucket-sorted CSR build ---
  k_bhist<<<dim3(512), B512, 0, stream>>>(edst, bcnt, E, nbuck);
  k_bscan<<<dim3(1), B512, 0, stream>>>(bcnt, bbase, bcur, nbuck);
  k_bscatter<<<dim3((E + 8191)/8192), B512, 0, stream>>>(esrc, edst, bcur, sortedp, E, nbuck);
  k_finesort<<<dim3(nbuck), B512, 0, stream>>>(sortedp, bbase, cend, dinv, n, (int*)hA);

  // --- fused MLP + conv1 transform: tp1(half, row-major) -> hA ---
  k_mega<<<dim3((n + 31)/32), B256, 0, stream>>>(x, W1, b1, b2, b3, b4,
                                                 whi, wlo, dinv, (__half*)hA, n);
  // --- agg1 -> hB ---
  k_agg<<<dim3((n+3)/4), B256, 0, stream>>>(cend, sortedp, dinv, (const __half*)hA, hB, n);

  // --- conv2: tp2(half) = (relu(agg1+bc1) @ Wc2.T)*dinv -> hA ---
  k_mgemm<128,128,128,1,5,4,2><<<dim3(G256), B512, 0, stream>>>(hB, Wc2, bc1, nullptr, dinv, hA, n);
  // --- agg2 -> hB ---
  k_agg<<<dim3((n+3)/4), B256, 0, stream>>>(cend, sortedp, dinv, (const __half*)hA, hB, n);

  // --- final: out = relu(agg2+bc2) @ W5.T + b5 ---
  k_mgemm<128,64,60,1,1,8,1><<<dim3(G512), B512, 0, stream>>>(hB, W5, bc2, b5, nullptr, out, n);
}

// Round 10
// 431.500 us; speedup vs baseline: 2.3324x; 1.0405x over previous
//
#include <hip/hip_runtime.h>
#include <hip/hip_fp16.h>

typedef __attribute__((ext_vector_type(8))) short bf16x8;
typedef __attribute__((ext_vector_type(4))) float f32x4;

__device__ __forceinline__ float frelu(float v){ return fmaxf(v, 0.f); }
__device__ __forceinline__ short f2bf(float f){
  unsigned u = __float_as_uint(f);
  unsigned r = (u + 0x7fffu + ((u>>16)&1u)) >> 16;
  return (short)r;
}
__device__ __forceinline__ float bf2f(short h){
  return __uint_as_float(((unsigned)(unsigned short)h) << 16);
}
__device__ __forceinline__ float4 addh4(float4 a, uint2 v){
  union { unsigned u; __half2 h; } p0, p1;
  p0.u = v.x; p1.u = v.y;
  a.x += __low2float(p0.h); a.y += __high2float(p0.h);
  a.z += __low2float(p1.h); a.w += __high2float(p1.h);
  return a;
}

// ---------- MFMA split-bf16 GEMM: Out = EPI( PRE(A) @ W.T ) ----------
// PRE: 0 id (fp32 A), 1 relu(a + bpre[k]) (fp32 A), 2 id (fp16 A)
// EPI: 1 +bpost (fp32 out), 2 relu(+bpost), 3 relu(+bpost)+A[node][col],
//      4 *dscale[node] (fp32 out), 5 *dscale[node] -> fp16 row-major out
template<int K, int BN, int COLS_REAL, int PRE, int EPI, int WRG, int WCG>
__global__ __launch_bounds__(512) void k_mgemm(const float* __restrict__ A,
    const float* __restrict__ W, const float* __restrict__ bpre,
    const float* __restrict__ bpost, const float* __restrict__ dscale,
    float* __restrict__ Out, int n)
{
  constexpr int BM = WRG*64;
  __shared__ __align__(16) short sAh[BM*32];
  __shared__ __align__(16) short sAl[BM*32];
  __shared__ __align__(16) short sWh[BN*32];
  __shared__ __align__(16) short sWl[BN*32];

  const int tid = threadIdx.x;
  const int nb0 = blockIdx.x * BM;
  const int l = tid & 63;
  const int w = tid >> 6;
  const int wr = w % WRG;
  const int wc = w / WRG;
  const int lrow = l & 15;
  const int koct = l >> 4;

  f32x4 acc[4][4];
  #pragma unroll
  for (int i=0;i<4;i++)
    #pragma unroll
    for (int j=0;j<4;j++) acc[i][j] = (f32x4){0.f,0.f,0.f,0.f};

  for (int kc = 0; kc < K/32; ++kc) {
    if (kc) __syncthreads();
    #pragma unroll
    for (int t = 0; t < BM/128; ++t) {
      int idx = tid + t*512;
      int row = idx >> 2, kq = idx & 3;
      int node = nb0 + row;
      float a[8];
      if constexpr (PRE == 2) {
        const __half* Ah = (const __half*)A;
        union { uint4 u; __half2 h[4]; } v;
        if (node < n) v.u = *(const uint4*)(Ah + (size_t)node*K + kc*32 + kq*8);
        else { v.u.x=0u; v.u.y=0u; v.u.z=0u; v.u.w=0u; }
        #pragma unroll
        for (int j=0;j<4;j++){
          a[2*j]   = __low2float(v.h[j]);
          a[2*j+1] = __high2float(v.h[j]);
        }
      } else {
        if (node < n) {
          const float* g = A + (size_t)node*K + kc*32 + kq*8;
          float4 v0 = *(const float4*)g;
          float4 v1 = *(const float4*)(g+4);
          a[0]=v0.x; a[1]=v0.y; a[2]=v0.z; a[3]=v0.w;
          a[4]=v1.x; a[5]=v1.y; a[6]=v1.z; a[7]=v1.w;
        } else {
          #pragma unroll
          for (int j=0;j<8;j++) a[j]=0.f;
        }
        if constexpr (PRE == 1) {
          const float* bp = bpre + kc*32 + kq*8;
          float4 b0 = *(const float4*)bp;
          float4 b1 = *(const float4*)(bp+4);
          a[0]=frelu(a[0]+b0.x); a[1]=frelu(a[1]+b0.y);
          a[2]=frelu(a[2]+b0.z); a[3]=frelu(a[3]+b0.w);
          a[4]=frelu(a[4]+b1.x); a[5]=frelu(a[5]+b1.y);
          a[6]=frelu(a[6]+b1.z); a[7]=frelu(a[7]+b1.w);
        }
      }
      union { short s[8]; bf16x8 v; } ph, pl;
      #pragma unroll
      for (int j=0;j<8;j++) {
        short h = f2bf(a[j]);
        ph.s[j] = h;
        pl.s[j] = f2bf(a[j] - bf2f(h));
      }
      int byte = (row<<6) | (kq<<4);
      byte ^= (row&7)<<4;
      *(bf16x8*)((char*)sAh + byte) = ph.v;
      *(bf16x8*)((char*)sAl + byte) = pl.v;
    }
    if (BN*4 >= 512 || tid < BN*4) {
      int idx = tid;
      int c = idx >> 2, kq = idx & 3;
      float a[8];
      if (COLS_REAL == BN || c < COLS_REAL) {
        const float* g = W + (size_t)c*K + kc*32 + kq*8;
        float4 v0 = *(const float4*)g;
        float4 v1 = *(const float4*)(g+4);
        a[0]=v0.x; a[1]=v0.y; a[2]=v0.z; a[3]=v0.w;
        a[4]=v1.x; a[5]=v1.y; a[6]=v1.z; a[7]=v1.w;
      } else {
        #pragma unroll
        for (int j=0;j<8;j++) a[j]=0.f;
      }
      union { short s[8]; bf16x8 v; } ph, pl;
      #pragma unroll
      for (int j=0;j<8;j++) {
        short h = f2bf(a[j]);
        ph.s[j] = h;
        pl.s[j] = f2bf(a[j] - bf2f(h));
      }
      int byte = (c<<6) | (kq<<4);
      byte ^= (c&7)<<4;
      *(bf16x8*)((char*)sWh + byte) = ph.v;
      *(bf16x8*)((char*)sWl + byte) = pl.v;
    }
    __syncthreads();
    bf16x8 fah[4], fal[4], fwh[4], fwl[4];
    #pragma unroll
    for (int rf=0; rf<4; ++rf) {
      int row = wr*64 + rf*16 + lrow;
      int byte = (row<<6) | (koct<<4);
      byte ^= (row&7)<<4;
      fah[rf] = *(const bf16x8*)((const char*)sAh + byte);
      fal[rf] = *(const bf16x8*)((const char*)sAl + byte);
    }
    #pragma unroll
    for (int cf=0; cf<4; ++cf) {
      int c = wc*64 + cf*16 + lrow;
      int byte = (c<<6) | (koct<<4);
      byte ^= (c&7)<<4;
      fwh[cf] = *(const bf16x8*)((const char*)sWh + byte);
      fwl[cf] = *(const bf16x8*)((const char*)sWl + byte);
    }
    #pragma unroll
    for (int rf=0; rf<4; ++rf)
      #pragma unroll
      for (int cf=0; cf<4; ++cf) {
        acc[rf][cf] = __builtin_amdgcn_mfma_f32_16x16x32_bf16(fah[rf], fwh[cf], acc[rf][cf], 0,0,0);
        acc[rf][cf] = __builtin_amdgcn_mfma_f32_16x16x32_bf16(fah[rf], fwl[cf], acc[rf][cf], 0,0,0);
        acc[rf][cf] = __builtin_amdgcn_mfma_f32_16x16x32_bf16(fal[rf], fwh[cf], acc[rf][cf], 0,0,0);
      }
  }
  const int crow = (l >> 4) * 4;
  float bpc[4];
  if constexpr (EPI==1 || EPI==2 || EPI==3) {
    #pragma unroll
    for (int cf=0; cf<4; ++cf) {
      int col = wc*64 + cf*16 + (l & 15);
      bpc[cf] = (COLS_REAL == BN || col < COLS_REAL) ? bpost[col] : 0.f;
    }
  }
  #pragma unroll
  for (int rf=0; rf<4; ++rf) {
    #pragma unroll
    for (int reg=0; reg<4; ++reg) {
      int row = wr*64 + rf*16 + crow + reg;
      int node = nb0 + row;
      if (node >= n) continue;
      float ds = 1.f;
      if constexpr (EPI==4 || EPI==5) ds = dscale[node];
      #pragma unroll
      for (int cf=0; cf<4; ++cf) {
        int col = wc*64 + cf*16 + (l & 15);
        if (COLS_REAL != BN && col >= COLS_REAL) continue;
        float v = acc[rf][cf][reg];
        if constexpr (EPI==1) v += bpc[cf];
        if constexpr (EPI==2) v = frelu(v + bpc[cf]);
        if constexpr (EPI==3) v = frelu(v + bpc[cf]) + A[(size_t)node*K + col];
        if constexpr (EPI==4) v *= ds;
        if constexpr (EPI==5) {
          v *= ds;
          ((__half*)Out)[(size_t)node*COLS_REAL + col] = __float2half_rn(v);
        } else {
          Out[(size_t)node*COLS_REAL + col] = v;
        }
      }
    }
  }
}

// ---------- weight pre-split into LDS-image layout (+ zero bcnt in block 0) ----------
__global__ __launch_bounds__(256) void k_wsplit(const float* __restrict__ W2,
    const float* __restrict__ W3, const float* __restrict__ W4,
    const float* __restrict__ Wc1, short* __restrict__ whi, short* __restrict__ wlo,
    int* __restrict__ bcnt)
{
  if (blockIdx.x == 0){
    bcnt[threadIdx.x] = 0;
    bcnt[threadIdx.x + 256] = 0;
  }
  int idx = blockIdx.x*256 + threadIdx.x;
  if (idx >= 57344) return;
  const float* src; int e, c, k, cbase;
  if (idx < 8192){ src=W2; e=idx; c=e>>6; k=e&63; cbase=0; }
  else if (idx < 24576){ src=W3; e=idx-8192; c=e>>7; k=e&127; cbase=8192; }
  else if (idx < 40960){ src=W4; e=idx-24576; c=e>>7; k=e&127; cbase=24576; }
  else { src=Wc1; e=idx-40960; c=e>>7; k=e&127; cbase=40960; }
  float v = src[e];
  short h = f2bf(v);
  short lo = f2bf(v - bf2f(h));
  int byte = ((c<<6) | ((k&31)<<1)) ^ ((c&7)<<4);
  int pos = cbase + (k>>5)*4096 + (byte>>1);
  whi[pos] = h; wlo[pos] = lo;
}

// ---------- fused MLP mega-kernel: x -> h1..h4 -> tp1 = (h4@Wc1^T)*dinv (fp16, row-major) ----------
__global__ __launch_bounds__(256) void k_mega(const float* __restrict__ x,
    const float* __restrict__ W1, const float* __restrict__ b1,
    const float* __restrict__ b2, const float* __restrict__ b3,
    const float* __restrict__ b4, const short* __restrict__ whi,
    const short* __restrict__ wlo, const float* __restrict__ dinv,
    __half* __restrict__ tp1, int n)
{
  __shared__ __align__(16) short sWh[4096], sWl[4096];
  __shared__ __align__(16) short bAh[4096], bAl[4096];
  __shared__ __align__(16) short bBh[4096], bBl[4096];
  __shared__ float sx[160];
  __shared__ float sW1[320];
  __shared__ float sb1[64];
  const int tid = threadIdx.x;
  const int nb0 = blockIdx.x*32;

  if (tid < 160){ int row = tid/5, col = tid - row*5; int node = nb0 + row;
    sx[tid] = (node < n) ? x[(size_t)node*5 + col] : 0.f; }
  if (tid < 64) sb1[tid] = b1[tid];
  for (int i = tid; i < 320; i += 256) sW1[i] = W1[i];
  __syncthreads();

  {
    int row = tid >> 3, c0 = (tid & 7)*8;
    float xr[5];
    #pragma unroll
    for (int k=0;k<5;k++) xr[k] = sx[row*5+k];
    #pragma unroll
    for (int j=0;j<8;j++){
      int c = c0 + j;
      float a = sb1[c];
      #pragma unroll
      for (int k=0;k<5;k++) a = fmaf(xr[k], sW1[c*5+k], a);
      a = frelu(a);
      short h = f2bf(a), lo = f2bf(a - bf2f(h));
      int byte = ((c>>5)<<11) + ((((row<<6)|((c&31)<<1))) ^ ((row&7)<<4));
      *(short*)((char*)bAh + byte) = h;
      *(short*)((char*)bAl + byte) = lo;
    }
  }

  const int l = tid & 63, w = tid >> 6;
  const int wr = w >> 1, wc = w & 1;
  const int lrow = l & 15, koct = l >> 4;
  const int arow = wr*16 + lrow;
  const int abyteNoKc = ((arow<<6)|(koct<<4)) ^ ((arow&7)<<4);
  int wbyte[4];
  #pragma unroll
  for (int cf=0; cf<4; ++cf){
    int c = wc*64 + cf*16 + lrow;
    wbyte[cf] = ((c<<6)|(koct<<4)) ^ ((c&7)<<4);
  }
  f32x4 acc[4];
  float res[4][4];

  auto run_layer = [&](const short* inH, const short* inL, int woff, int nkc){
    #pragma unroll
    for (int cf=0; cf<4; ++cf) acc[cf] = (f32x4){0.f,0.f,0.f,0.f};
    for (int kc=0; kc<nkc; ++kc){
      __syncthreads();
      {
        const bf16x8* gh = (const bf16x8*)(whi + woff + kc*4096);
        const bf16x8* gl = (const bf16x8*)(wlo + woff + kc*4096);
        ((bf16x8*)sWh)[tid*2]   = gh[tid*2];
        ((bf16x8*)sWh)[tid*2+1] = gh[tid*2+1];
        ((bf16x8*)sWl)[tid*2]   = gl[tid*2];
        ((bf16x8*)sWl)[tid*2+1] = gl[tid*2+1];
      }
      __syncthreads();
      int ab = (kc<<11) + abyteNoKc;
      bf16x8 fah = *(const bf16x8*)((const char*)inH + ab);
      bf16x8 fal = *(const bf16x8*)((const char*)inL + ab);
      #pragma unroll
      for (int cf=0; cf<4; ++cf){
        bf16x8 fwh = *(const bf16x8*)((const char*)sWh + wbyte[cf]);
        bf16x8 fwl = *(const bf16x8*)((const char*)sWl + wbyte[cf]);
        acc[cf] = __builtin_amdgcn_mfma_f32_16x16x32_bf16(fah, fwh, acc[cf], 0,0,0);
        acc[cf] = __builtin_amdgcn_mfma_f32_16x16x32_bf16(fah, fwl, acc[cf], 0,0,0);
        acc[cf] = __builtin_amdgcn_mfma_f32_16x16x32_bf16(fal, fwh, acc[cf], 0,0,0);
      }
    }
  };
  auto store_buf = [&](short* outH, short* outL, int cf, int reg, float v){
    int row = wr*16 + koct*4 + reg;
    int col = wc*64 + cf*16 + lrow;
    short h = f2bf(v), lo = f2bf(v - bf2f(h));
    int byte = ((col>>5)<<11) + (((row<<6)|((col&31)<<1)) ^ ((row&7)<<4));
    *(short*)((char*)outH + byte) = h;
    *(short*)((char*)outL + byte) = lo;
  };

  run_layer(bAh, bAl, 0, 2);
  #pragma unroll
  for (int cf=0; cf<4; ++cf){
    float bb = b2[wc*64 + cf*16 + lrow];
    #pragma unroll
    for (int reg=0; reg<4; ++reg){
      float v = frelu(acc[cf][reg] + bb);
      res[cf][reg] = v;
      store_buf(bBh, bBl, cf, reg, v);
    }
  }
  run_layer(bBh, bBl, 8192, 4);
  #pragma unroll
  for (int cf=0; cf<4; ++cf){
    float bb = b3[wc*64 + cf*16 + lrow];
    #pragma unroll
    for (int reg=0; reg<4; ++reg){
      float v = frelu(acc[cf][reg] + bb) + res[cf][reg];
      res[cf][reg] = v;
      store_buf(bAh, bAl, cf, reg, v);
    }
  }
  run_layer(bAh, bAl, 24576, 4);
  #pragma unroll
  for (int cf=0; cf<4; ++cf){
    float bb = b4[wc*64 + cf*16 + lrow];
    #pragma unroll
    for (int reg=0; reg<4; ++reg){
      float v = frelu(acc[cf][reg] + bb) + res[cf][reg];
      store_buf(bBh, bBl, cf, reg, v);
    }
  }
  run_layer(bBh, bBl, 40960, 4);
  #pragma unroll
  for (int reg=0; reg<4; ++reg){
    int row = wr*16 + koct*4 + reg;
    int node = nb0 + row;
    float di = dinv[min(node, n-1)];
    #pragma unroll
    for (int cf=0; cf<4; ++cf){
      int col = wc*64 + cf*16 + lrow;
      if (node < n)
        tp1[(size_t)node*128 + col] = __float2half_rn(acc[cf][reg]*di);
    }
  }
}

// ---------- bucket sort of edges by dst (256 nodes / bucket) ----------
__global__ __launch_bounds__(512) void k_bhist(const int* __restrict__ dst,
    int* __restrict__ bcnt, int E, int nbuck){
  __shared__ int l[512];
  int tid = threadIdx.x;
  if (tid < nbuck) l[tid]=0;
  __syncthreads();
  const int E4 = E >> 2;
  const int4* d4 = (const int4*)dst;
  for (int i = blockIdx.x*512 + tid; i < E4; i += gridDim.x*512){
    int4 v = d4[i];
    atomicAdd(&l[((unsigned)v.x)>>8], 1);
    atomicAdd(&l[((unsigned)v.y)>>8], 1);
    atomicAdd(&l[((unsigned)v.z)>>8], 1);
    atomicAdd(&l[((unsigned)v.w)>>8], 1);
  }
  for (int e = (E4<<2) + blockIdx.x*512 + tid; e < E; e += gridDim.x*512)
    atomicAdd(&l[((unsigned)dst[e])>>8], 1);
  __syncthreads();
  if (tid < nbuck && l[tid]) atomicAdd(&bcnt[tid], l[tid]);
}
__global__ __launch_bounds__(512) void k_bscan(const int* __restrict__ bcnt,
    int* __restrict__ bbase, int* __restrict__ bcur, int nbuck){
  __shared__ int sc[512];
  int tid = threadIdx.x;
  int v = (tid<nbuck) ? bcnt[tid] : 0;
  sc[tid]=v; __syncthreads();
  for (int off=1; off<512; off<<=1){
    int t = (tid>=off)? sc[tid-off] : 0;
    __syncthreads();
    sc[tid]+=t;
    __syncthreads();
  }
  if (tid<nbuck){ bbase[tid]=sc[tid]-v; bcur[tid]=sc[tid]-v; }
  if (tid==nbuck-1) bbase[nbuck]=sc[tid];
}
__global__ __launch_bounds__(512) void k_bscatter(const int* __restrict__ src,
    const int* __restrict__ dst, int* __restrict__ bcur,
    unsigned* __restrict__ sorted, int E, int nbuck)
{
  __shared__ int lcnt[512];
  __shared__ int lbase[512];
  int tid = threadIdx.x;
  if (tid < nbuck) lcnt[tid]=0;
  __syncthreads();
  int e0 = blockIdx.x*8192;
  int e1 = min(e0+8192, E);
  for (int e = e0+tid; e < e1; e += 512)
    atomicAdd(&lcnt[((unsigned)dst[e])>>8], 1);
  __syncthreads();
  if (tid < nbuck) lbase[tid] = lcnt[tid] ? atomicAdd(&bcur[tid], lcnt[tid]) : 0;
  __syncthreads();
  if (tid < nbuck) lcnt[tid]=0;
  __syncthreads();
  for (int e = e0+tid; e < e1; e += 512){
    int d = dst[e];
    int k = ((unsigned)d)>>8;
    int pos = lbase[k] + atomicAdd(&lcnt[k], 1);
    sorted[pos] = (((unsigned)src[e])<<8) | ((unsigned)d & 255u);
  }
}
__global__ __launch_bounds__(512) void k_finesort(unsigned* __restrict__ sorted,
    const int* __restrict__ bbase, int* __restrict__ cend,
    float* __restrict__ dinv, int n, int* __restrict__ fb)
{
  constexpr int CAP = 10240;   // mean bucket = 8192, sigma ~ 90; +22 sigma
  __shared__ int lsorted[CAP];
  __shared__ int cnt[256], cur[256], sc[256];
  const int k = blockIdx.x;
  const int base = bbase[k], endb = bbase[k+1];
  const int m = endb - base;
  const int node0 = k<<8;
  const int tid = threadIdx.x;
  if (tid<256) cnt[tid]=0;
  __syncthreads();
  for (int i=tid; i<m; i+=512) atomicAdd(&cnt[sorted[base+i]&255u], 1);
  __syncthreads();
  int v=0;
  if (tid<256){ v=cnt[tid]; sc[tid]=v; }
  __syncthreads();
  for (int off=1; off<256; off<<=1){
    int t=0;
    if (tid>=off && tid<256) t=sc[tid-off];
    __syncthreads();
    if (tid<256) sc[tid]+=t;
    __syncthreads();
  }
  if (tid<256){
    cur[tid]=sc[tid]-v;
    int node = node0 + tid;
    if (node < n){
      cend[node] = base + sc[tid];
      dinv[node] = rsqrtf((float)v + 1.0f);
    }
  }
  __syncthreads();
  if (m <= CAP){
    for (int i=tid; i<m; i+=512){
      unsigned p = sorted[base+i];
      int pos = atomicAdd(&cur[p&255u], 1);
      lsorted[pos] = (int)(p>>8);
    }
    __syncthreads();
    for (int i=tid; i<m; i+=512) sorted[base+i] = (unsigned)lsorted[i];
  } else {
    for (int i=tid; i<m; i+=512) fb[base+i] = (int)sorted[base+i];
    __syncthreads();
    for (int i=tid; i<m; i+=512){
      unsigned p = (unsigned)fb[base+i];
      int pos = atomicAdd(&cur[p&255u], 1);
      sorted[base+pos] = p>>8;
    }
  }
}

// ---------- gather aggregation: outh[d] = relu(dinv[d]*(tp[d]+sum tp[s]) + bc) fp16 ----------
// one wave per node; sub-wave (32 lanes x 8 B = 256 B row) per edge.
__global__ __launch_bounds__(256) void k_agg(const int* __restrict__ cend,
    const unsigned* __restrict__ srcs, const float* __restrict__ dinv,
    const float* __restrict__ bpre, const __half* __restrict__ tp,
    __half* __restrict__ outh, int n)
{
  int node = blockIdx.x*4 + (threadIdx.x>>6);
  if (node >= n) return;
  const int lane = threadIdx.x & 63;
  const int sub = lane >> 5, li = lane & 31;
  const uint2* tpq = (const uint2*)tp;   // row = 32 x 8 B
  int beg = (node==0) ? 0 : cend[node-1];
  int end = cend[node];
  float4 acc = {0.f,0.f,0.f,0.f};
  int e = beg + sub;
  for (; e + 6 < end; e += 8){
    unsigned s0 = __builtin_nontemporal_load(srcs + e);
    unsigned s1 = __builtin_nontemporal_load(srcs + e + 2);
    unsigned s2 = __builtin_nontemporal_load(srcs + e + 4);
    unsigned s3 = __builtin_nontemporal_load(srcs + e + 6);
    uint2 v0 = tpq[(size_t)s0*32 + li];
    uint2 v1 = tpq[(size_t)s1*32 + li];
    uint2 v2 = tpq[(size_t)s2*32 + li];
    uint2 v3 = tpq[(size_t)s3*32 + li];
    acc = addh4(acc, v0);
    acc = addh4(acc, v1);
    acc = addh4(acc, v2);
    acc = addh4(acc, v3);
  }
  for (; e < end; e += 2){
    unsigned s = __builtin_nontemporal_load(srcs + e);
    uint2 v = tpq[(size_t)s*32 + li];
    acc = addh4(acc, v);
  }
  acc.x += __shfl_xor(acc.x, 32, 64);
  acc.y += __shfl_xor(acc.y, 32, 64);
  acc.z += __shfl_xor(acc.z, 32, 64);
  acc.w += __shfl_xor(acc.w, 32, 64);
  if (sub == 0){
    uint2 v = tpq[(size_t)node*32 + li];   // self-loop term
    acc = addh4(acc, v);
    float di = dinv[node];
    float4 bc = *(const float4*)(bpre + li*4);
    float rx = frelu(fmaf(acc.x, di, bc.x));
    float ry = frelu(fmaf(acc.y, di, bc.y));
    float rz = frelu(fmaf(acc.z, di, bc.z));
    float rw = frelu(fmaf(acc.w, di, bc.w));
    union { __half2 h[2]; uint2 u; } o;
    o.h[0] = __halves2half2(__float2half_rn(rx), __float2half_rn(ry));
    o.h[1] = __halves2half2(__float2half_rn(rz), __float2half_rn(rw));
    *(uint2*)(outh + (size_t)node*128 + li*4) = o.u;
  }
}

extern "C" void kernel_launch(void* const* d_in, const int* in_sizes, int n_in,
                              void* d_out, int out_size, void* d_ws, size_t ws_size,
                              hipStream_t stream)
{
  const float* x   = (const float*)d_in[0];
  const int*   ei  = (const int*)d_in[1];
  const float *W1=(const float*)d_in[2],  *b1=(const float*)d_in[3];
  const float *W2=(const float*)d_in[4],  *b2=(const float*)d_in[5];
  const float *W3=(const float*)d_in[6],  *b3=(const float*)d_in[7];
  const float *W4=(const float*)d_in[8],  *b4=(const float*)d_in[9];
  const float *Wc1=(const float*)d_in[10],*bc1=(const float*)d_in[11];
  const float *Wc2=(const float*)d_in[12],*bc2=(const float*)d_in[13];
  const float *W5=(const float*)d_in[14], *b5=(const float*)d_in[15];
  float* out = (float*)d_out;

  const int n = in_sizes[0] / 5;
  const int E = in_sizes[1] / 2;
  const int* esrc = ei;
  const int* edst = ei + E;
  const int nbuck = (n + 255) >> 8;

  dim3 B256(256), B512(512);
  const int G256 = (n + 255)/256;
  const int G512 = (n + 511)/512;

  // workspace layout (~117 MB)
  char* p = (char*)d_ws;
  float* hA    = (float*)p;           p += (size_t)n*128*4;
  float* hB    = (float*)p;           p += (size_t)n*128*4;
  float* dinv  = (float*)p;           p += (size_t)n*4;
  int*   cend  = (int*)p;             p += (size_t)n*4;
  unsigned* sortedp = (unsigned*)p;   p += (size_t)E*4;
  int*   bcnt  = (int*)p;             p += 512*4;
  int*   bbase = (int*)p;             p += 513*4;
  int*   bcur  = (int*)p;             p += 512*4;
  short* whi   = (short*)p;           p += 57344*2;
  short* wlo   = (short*)p;           p += 57344*2;

  // --- weight pre-split (block 0 zeroes bcnt) ---
  k_wsplit<<<dim3(224), B256, 0, stream>>>(W2, W3, W4, Wc1, whi, wlo, bcnt);

  // --- bucket-sorted CSR build ---
  k_bhist<<<dim3(512), B512, 0, stream>>>(edst, bcnt, E, nbuck);
  k_bscan<<<dim3(1), B512, 0, stream>>>(bcnt, bbase, bcur, nbuck);
  k_bscatter<<<dim3((E + 8191)/8192), B512, 0, stream>>>(esrc, edst, bcur, sortedp, E, nbuck);
  k_finesort<<<dim3(nbuck), B512, 0, stream>>>(sortedp, bbase, cend, dinv, n, (int*)hA);

  // --- fused MLP + conv1 transform: tp1(half, row-major) -> hA ---
  k_mega<<<dim3((n + 31)/32), B256, 0, stream>>>(x, W1, b1, b2, b3, b4,
                                                 whi, wlo, dinv, (__half*)hA, n);
  // --- agg1 (+bc1+relu, fp16) -> hB ---
  k_agg<<<dim3((n+3)/4), B256, 0, stream>>>(cend, sortedp, dinv, bc1,
                                            (const __half*)hA, (__half*)hB, n);

  // --- conv2: tp2(half) = (relu-agg1 @ Wc2.T)*dinv -> hA ---
  k_mgemm<128,128,128,2,5,4,2><<<dim3(G256), B512, 0, stream>>>(hB, Wc2, nullptr, nullptr, dinv, hA, n);

  // --- agg2 (+bc2+relu, fp16) -> hB ---
  k_agg<<<dim3((n+3)/4), B256, 0, stream>>>(cend, sortedp, dinv, bc2,
                                            (const __half*)hA, (__half*)hB, n);

  // --- final: out = relu-agg2 @ W5.T + b5 ---
  k_mgemm<128,64,60,2,1,8,1><<<dim3(G512), B512, 0, stream>>>(hB, W5, nullptr, b5, nullptr, out, n);
}